// Round 11
// baseline (364.745 us; speedup 1.0000x reference)
//
#include <hip/hip_runtime.h>
#include <hip/hip_cooperative_groups.h>
#include <math.h>

namespace cg = cooperative_groups;

#define DIM_IN 128
#define DIM_H 64
#define DIM_OUT 16
#define NBSHIFT 8  // 256 nodes per bucket
#define CHUNK 8192

typedef __attribute__((ext_vector_type(8))) short bf16x8;
typedef __attribute__((ext_vector_type(4))) float f32x4;

__device__ __forceinline__ ushort f2bf(float f) {
  uint u = __float_as_uint(f);
  return (ushort)((u + 0x7FFF + ((u >> 16) & 1)) >> 16);
}
__device__ __forceinline__ float bf2f(ushort s) {
  return __uint_as_float(((uint)s) << 16);
}
__device__ __forceinline__ uint cvtpk(float lo, float hi) {
  uint r;
  asm("v_cvt_pk_bf16_f32 %0, %1, %2" : "=v"(r) : "v"(lo), "v"(hi));
  return r;
}

// ============ CSR build: single cooperative kernel, 6 phases ============
// esrc[i] packs (bf16(dinv[src]) << 17) | src  (dinv<=1 -> bf16<=0x3F80 fits
// 14 bits; src < 2^17).
__global__ __launch_bounds__(256) void k_csrbuild(
    const int* __restrict__ src, const int* __restrict__ dst, int E, int n,
    int NC, int NB, int* __restrict__ chunkhist, int* __restrict__ cstart,
    int* __restrict__ gbhist, int* __restrict__ bbase, uint* __restrict__ pairs,
    int* __restrict__ degi, float* __restrict__ dinv, int* __restrict__ rowptr,
    uint* __restrict__ esrc) {
  cg::grid_group grid = cg::this_grid();
  __shared__ int lh[512];
  __shared__ int nh[256];
  __shared__ int ncur[256];
  const int t = threadIdx.x;
  const int bid = blockIdx.x;
  const int nblk = gridDim.x;

  // Phase A: per-chunk bucket histogram
  for (int c = bid; c < NC; c += nblk) {
    lh[t] = 0;
    lh[t + 256] = 0;
    __syncthreads();
    int e0 = c * CHUNK, e1 = min(E, e0 + CHUNK);
    for (int i = e0 + t; i < e1; i += 256) atomicAdd(&lh[dst[i] >> NBSHIFT], 1);
    __syncthreads();
    chunkhist[c * 512 + t] = lh[t];
    chunkhist[c * 512 + t + 256] = lh[t + 256];
    __syncthreads();
  }
  grid.sync();

  // Phase B: per-bucket exclusive scan across chunks
  for (int b = bid; b < 512; b += nblk) {
    int v = (t < NC) ? chunkhist[t * 512 + b] : 0;
    lh[t] = v;
    __syncthreads();
    for (int off = 1; off < 256; off <<= 1) {
      int add = (t >= off) ? lh[t - off] : 0;
      __syncthreads();
      lh[t] += add;
      __syncthreads();
    }
    if (t < NC) cstart[t * 512 + b] = lh[t] - v;
    if (t == 255) gbhist[b] = lh[255];
    __syncthreads();
  }
  grid.sync();

  // Phase C: block 0 scans gbhist[512] -> bbase
  if (bid == 0) {
    int v0 = gbhist[t], v1 = gbhist[t + 256];
    lh[t] = v0;
    lh[t + 256] = v1;
    __syncthreads();
    for (int off = 1; off < 256; off <<= 1) {
      int a0 = (t >= off) ? lh[t - off] : 0;
      int a1 = (t >= off) ? lh[256 + t - off] : 0;
      __syncthreads();
      lh[t] += a0;
      lh[256 + t] += a1;
      __syncthreads();
    }
    int tot0 = lh[255];
    bbase[t] = lh[t] - v0;
    bbase[t + 256] = lh[256 + t] - v1 + tot0;
  }
  grid.sync();

  // Phase D: partition into bucket regions (pairs = (src<<8)|dst8)
  for (int c = bid; c < NC; c += nblk) {
    lh[t] = cstart[c * 512 + t] + bbase[t];
    lh[t + 256] = cstart[c * 512 + t + 256] + bbase[t + 256];
    __syncthreads();
    int e0 = c * CHUNK, e1 = min(E, e0 + CHUNK);
    for (int i = e0 + t; i < e1; i += 256) {
      int d = dst[i];
      int pos = atomicAdd(&lh[d >> NBSHIFT], 1);
      pairs[pos] = ((uint)src[i] << 8) | ((uint)d & 255u);
    }
    __syncthreads();
  }
  grid.sync();

  // Phase E: per-bucket node histogram + scan -> degi/dinv/rowptr (bucket=bid)
  int base = 0, cnt = 0;
  if (bid < NB) {
    base = bbase[bid];
    cnt = gbhist[bid];
    nh[t] = 0;
    __syncthreads();
    for (int i = t; i < cnt; i += 256) atomicAdd(&nh[pairs[base + i] & 255u], 1);
    __syncthreads();
    int node = (bid << NBSHIFT) + t;
    int v = nh[t];
    if (node < n) {
      degi[node] = v;
      dinv[node] = rsqrtf((float)v + 1.0f);
    }
    __syncthreads();
    for (int off = 1; off < 256; off <<= 1) {
      int add = (t >= off) ? nh[t - off] : 0;
      __syncthreads();
      nh[t] += add;
      __syncthreads();
    }
    int excl = nh[t] - v;
    if (node < n) rowptr[node] = base + excl;
    ncur[t] = base + excl;
  }
  grid.sync();  // all dinv visible

  // Phase F: scatter packed esrc (ncur persists in LDS)
  if (bid < NB) {
    for (int i = t; i < cnt; i += 256) {
      uint p = pairs[base + i];
      int pos = atomicAdd(&ncur[p & 255u], 1);
      uint s = p >> 8;
      esrc[pos] = ((uint)f2bf(dinv[s]) << 17) | s;
    }
  }
}

// ======================= GEMM1 (MFMA bf16): h1 = x @ W1 =======================
__global__ __launch_bounds__(256, 4) void k_gemm1m(const float* __restrict__ x,
                                                   const float* __restrict__ W,
                                                   ushort* __restrict__ h, int n,
                                                   int nTiles) {
  const int t = threadIdx.x;
  const int lane = t & 63;
  const int wid = blockIdx.x * 4 + (t >> 6);
  const int nW = gridDim.x * 4;
  const int cc = lane & 15;
  const int kb = (lane >> 4) * 8;

  bf16x8 bfrag[4][4];
#pragma unroll
  for (int kc = 0; kc < 4; ++kc)
#pragma unroll
    for (int nt = 0; nt < 4; ++nt) {
      union { bf16x8 v; uint u[4]; } fb;
#pragma unroll
      for (int j = 0; j < 4; ++j) {
        float lo = W[(size_t)(kc * 32 + kb + 2 * j) * DIM_H + nt * 16 + cc];
        float hi = W[(size_t)(kc * 32 + kb + 2 * j + 1) * DIM_H + nt * 16 + cc];
        fb.u[j] = cvtpk(lo, hi);
      }
      bfrag[kc][nt] = fb.v;
    }

  for (int tile = wid; tile < nTiles; tile += nW) {
    int row0 = tile * 16;
    int ra = row0 + cc;
    if (ra > n - 1) ra = n - 1;
    const float* xp = x + (size_t)ra * DIM_IN;
    f32x4 acc[4] = {{0.f, 0.f, 0.f, 0.f},
                    {0.f, 0.f, 0.f, 0.f},
                    {0.f, 0.f, 0.f, 0.f},
                    {0.f, 0.f, 0.f, 0.f}};
#pragma unroll
    for (int kc = 0; kc < 4; ++kc) {
      float4 a0 = *(const float4*)(xp + kc * 32 + kb);
      float4 a1 = *(const float4*)(xp + kc * 32 + kb + 4);
      union { bf16x8 v; uint u[4]; } fa;
      fa.u[0] = cvtpk(a0.x, a0.y);
      fa.u[1] = cvtpk(a0.z, a0.w);
      fa.u[2] = cvtpk(a1.x, a1.y);
      fa.u[3] = cvtpk(a1.z, a1.w);
#pragma unroll
      for (int nt = 0; nt < 4; ++nt)
        acc[nt] = __builtin_amdgcn_mfma_f32_16x16x32_bf16(fa.v, bfrag[kc][nt],
                                                          acc[nt], 0, 0, 0);
    }
    int rbase = row0 + (lane >> 4) * 4;
#pragma unroll
    for (int nt = 0; nt < 4; ++nt) {
      int col = nt * 16 + cc;
#pragma unroll
      for (int j = 0; j < 4; ++j) {
        int r = rbase + j;
        if (r < n) h[(size_t)r * DIM_H + col] = f2bf(acc[nt][j]);
      }
    }
  }
}

// ============ GEMM2: h2(bf16) = agg1r(bf16, already relu'd) @ W2 ============
__global__ __launch_bounds__(256) void k_gemm2(const ushort* __restrict__ a,
                                               const float* __restrict__ W,
                                               ushort* __restrict__ h2, int n) {
  __shared__ float Ws[64][16];
  const int t = threadIdx.x;
  for (int i = t; i < 64 * 16; i += 256) Ws[i >> 4][i & 15] = W[i];
  __syncthreads();
  int r = blockIdx.x * 256 + t;
  if (r >= n) return;
  const uint4* ap = (const uint4*)(a + (size_t)r * DIM_H);
  float acc[16] = {};
#pragma unroll
  for (int k8 = 0; k8 < 8; ++k8) {
    uint4 v = ap[k8];
    uint w[4] = {v.x, v.y, v.z, v.w};
#pragma unroll
    for (int p = 0; p < 4; ++p) {
      float v0 = bf2f((ushort)(w[p] & 0xffff));
      float v1 = bf2f((ushort)(w[p] >> 16));
      int k = k8 * 8 + p * 2;
#pragma unroll
      for (int j = 0; j < 16; ++j) acc[j] = fmaf(v0, Ws[k][j], acc[j]);
#pragma unroll
      for (int j = 0; j < 16; ++j) acc[j] = fmaf(v1, Ws[k + 1][j], acc[j]);
    }
  }
  ushort4* hp = (ushort4*)(h2 + (size_t)r * DIM_OUT);
#pragma unroll
  for (int q = 0; q < 4; ++q) {
    ushort4 o;
    o.x = f2bf(acc[q * 4 + 0]);
    o.y = f2bf(acc[q * 4 + 1]);
    o.z = f2bf(acc[q * 4 + 2]);
    o.w = f2bf(acc[q * 4 + 3]);
    hp[q] = o;
  }
}

// ======================= gather aggregation =======================

// layer 1: one wave per node; q=lane&15 owns cols 4q..4q+3, g=lane>>4 walks
// edges j+g, j+4+g, j+8+g, j+12+g. esrc packed (weight bf16 | src). Output is
// relu(agg + self + bias) in bf16 (relu pre-applied for GEMM2).
__global__ __launch_bounds__(256) void k_gather64(const ushort* __restrict__ h,
                                                  const uint* __restrict__ esrc,
                                                  const int* __restrict__ rowptr,
                                                  const int* __restrict__ deg,
                                                  const float* __restrict__ dinv,
                                                  const float* __restrict__ b,
                                                  ushort* __restrict__ out, int n) {
  int node = blockIdx.x * 4 + (threadIdx.x >> 6);
  int lane = threadIdx.x & 63;
  int g = lane >> 4;
  int q = lane & 15;
  if (node >= n) return;
  int start = rowptr[node];
  int cnt = deg[node];
  float dd = dinv[node];
  float a0 = 0.f, a1 = 0.f, a2 = 0.f, a3 = 0.f;
  for (int j0 = 0; j0 < cnt; j0 += 64) {
    int rem = cnt - j0;
    if (rem > 64) rem = 64;
    uint p_l = (lane < rem) ? esrc[start + j0 + lane] : 0u;
    int s_l = (int)(p_l & 0x1FFFFu);
    float w_l = bf2f((ushort)(p_l >> 17)) * dd;  // 0 for padded lanes
    for (int j = 0; j < rem; j += 16) {
      int i0 = j + g, i1 = j + 4 + g, i2 = j + 8 + g, i3 = j + 12 + g;
      int s0 = __shfl(s_l, i0);
      float w0 = __shfl(w_l, i0);
      int s1 = __shfl(s_l, i1);
      float w1 = __shfl(w_l, i1);
      int s2 = __shfl(s_l, i2);
      float w2 = __shfl(w_l, i2);
      int s3 = __shfl(s_l, i3);
      float w3 = __shfl(w_l, i3);
      uint2 v0 = *(const uint2*)(h + (size_t)s0 * DIM_H + q * 4);
      uint2 v1 = *(const uint2*)(h + (size_t)s1 * DIM_H + q * 4);
      uint2 v2 = *(const uint2*)(h + (size_t)s2 * DIM_H + q * 4);
      uint2 v3 = *(const uint2*)(h + (size_t)s3 * DIM_H + q * 4);
      a0 = fmaf(bf2f((ushort)(v0.x & 0xffff)), w0, a0);
      a1 = fmaf(bf2f((ushort)(v0.x >> 16)), w0, a1);
      a2 = fmaf(bf2f((ushort)(v0.y & 0xffff)), w0, a2);
      a3 = fmaf(bf2f((ushort)(v0.y >> 16)), w0, a3);
      a0 = fmaf(bf2f((ushort)(v1.x & 0xffff)), w1, a0);
      a1 = fmaf(bf2f((ushort)(v1.x >> 16)), w1, a1);
      a2 = fmaf(bf2f((ushort)(v1.y & 0xffff)), w1, a2);
      a3 = fmaf(bf2f((ushort)(v1.y >> 16)), w1, a3);
      a0 = fmaf(bf2f((ushort)(v2.x & 0xffff)), w2, a0);
      a1 = fmaf(bf2f((ushort)(v2.x >> 16)), w2, a1);
      a2 = fmaf(bf2f((ushort)(v2.y & 0xffff)), w2, a2);
      a3 = fmaf(bf2f((ushort)(v2.y >> 16)), w2, a3);
      a0 = fmaf(bf2f((ushort)(v3.x & 0xffff)), w3, a0);
      a1 = fmaf(bf2f((ushort)(v3.x >> 16)), w3, a1);
      a2 = fmaf(bf2f((ushort)(v3.y & 0xffff)), w3, a2);
      a3 = fmaf(bf2f((ushort)(v3.y >> 16)), w3, a3);
    }
  }
  a0 += __shfl_xor(a0, 16); a0 += __shfl_xor(a0, 32);
  a1 += __shfl_xor(a1, 16); a1 += __shfl_xor(a1, 32);
  a2 += __shfl_xor(a2, 16); a2 += __shfl_xor(a2, 32);
  a3 += __shfl_xor(a3, 16); a3 += __shfl_xor(a3, 32);
  if (g == 0) {
    uint2 sv = *(const uint2*)(h + (size_t)node * DIM_H + q * 4);
    float s2 = dd * dd;
    a0 = fmaxf(fmaf(bf2f((ushort)(sv.x & 0xffff)), s2, a0) + b[4 * q + 0], 0.f);
    a1 = fmaxf(fmaf(bf2f((ushort)(sv.x >> 16)), s2, a1) + b[4 * q + 1], 0.f);
    a2 = fmaxf(fmaf(bf2f((ushort)(sv.y & 0xffff)), s2, a2) + b[4 * q + 2], 0.f);
    a3 = fmaxf(fmaf(bf2f((ushort)(sv.y >> 16)), s2, a3) + b[4 * q + 3], 0.f);
    uint lo = cvtpk(a0, a1);
    uint hi = cvtpk(a2, a3);
    *(uint2*)(out + (size_t)node * DIM_H + q * 4) = make_uint2(lo, hi);
  }
}

// layer 2: 16 lanes per node; c=lane&3 owns cols 4c..4c+3, e=(lane>>2)&3 picks
// edges e,4+e,8+e,12+e. esrc packed. Fused self+bias+log_softmax. out f32.
__global__ __launch_bounds__(256) void k_gather16(const ushort* __restrict__ h,
                                                  const uint* __restrict__ esrc,
                                                  const int* __restrict__ rowptr,
                                                  const int* __restrict__ deg,
                                                  const float* __restrict__ dinv,
                                                  const float* __restrict__ b,
                                                  float* __restrict__ out, int n) {
  int node = blockIdx.x * 16 + (threadIdx.x >> 4);
  int lane = threadIdx.x & 63;
  int lane16 = lane & 15;
  int gbase = lane & 48;
  int e = (lane >> 2) & 3;
  int c = lane & 3;
  if (node >= n) return;
  int start = rowptr[node];
  int cnt = deg[node];
  float dd = dinv[node];
  const int iA = gbase + e, iB = gbase + 4 + e, iC = gbase + 8 + e,
            iD = gbase + 12 + e;
  float a0 = 0.f, a1 = 0.f, a2 = 0.f, a3 = 0.f;
  for (int j0 = 0; j0 < cnt; j0 += 16) {
    int rem = cnt - j0;
    if (rem > 16) rem = 16;
    uint p_l = (lane16 < rem) ? esrc[start + j0 + lane16] : 0u;
    int s_l = (int)(p_l & 0x1FFFFu);
    float w_l = bf2f((ushort)(p_l >> 17)) * dd;
    int sA = __shfl(s_l, iA);
    float wA = __shfl(w_l, iA);
    int sB = __shfl(s_l, iB);
    float wB = __shfl(w_l, iB);
    int sC = __shfl(s_l, iC);
    float wC = __shfl(w_l, iC);
    int sD = __shfl(s_l, iD);
    float wD = __shfl(w_l, iD);
    uint2 vA = *(const uint2*)(h + (size_t)sA * DIM_OUT + c * 4);
    uint2 vB = *(const uint2*)(h + (size_t)sB * DIM_OUT + c * 4);
    uint2 vC = *(const uint2*)(h + (size_t)sC * DIM_OUT + c * 4);
    uint2 vD = *(const uint2*)(h + (size_t)sD * DIM_OUT + c * 4);
    a0 = fmaf(bf2f((ushort)(vA.x & 0xffff)), wA, a0);
    a1 = fmaf(bf2f((ushort)(vA.x >> 16)), wA, a1);
    a2 = fmaf(bf2f((ushort)(vA.y & 0xffff)), wA, a2);
    a3 = fmaf(bf2f((ushort)(vA.y >> 16)), wA, a3);
    a0 = fmaf(bf2f((ushort)(vB.x & 0xffff)), wB, a0);
    a1 = fmaf(bf2f((ushort)(vB.x >> 16)), wB, a1);
    a2 = fmaf(bf2f((ushort)(vB.y & 0xffff)), wB, a2);
    a3 = fmaf(bf2f((ushort)(vB.y >> 16)), wB, a3);
    a0 = fmaf(bf2f((ushort)(vC.x & 0xffff)), wC, a0);
    a1 = fmaf(bf2f((ushort)(vC.x >> 16)), wC, a1);
    a2 = fmaf(bf2f((ushort)(vC.y & 0xffff)), wC, a2);
    a3 = fmaf(bf2f((ushort)(vC.y >> 16)), wC, a3);
    a0 = fmaf(bf2f((ushort)(vD.x & 0xffff)), wD, a0);
    a1 = fmaf(bf2f((ushort)(vD.x >> 16)), wD, a1);
    a2 = fmaf(bf2f((ushort)(vD.y & 0xffff)), wD, a2);
    a3 = fmaf(bf2f((ushort)(vD.y >> 16)), wD, a3);
  }
  a0 += __shfl_xor(a0, 4); a0 += __shfl_xor(a0, 8);
  a1 += __shfl_xor(a1, 4); a1 += __shfl_xor(a1, 8);
  a2 += __shfl_xor(a2, 4); a2 += __shfl_xor(a2, 8);
  a3 += __shfl_xor(a3, 4); a3 += __shfl_xor(a3, 8);
  uint2 sv = *(const uint2*)(h + (size_t)node * DIM_OUT + c * 4);
  float s2 = dd * dd;
  a0 = fmaf(bf2f((ushort)(sv.x & 0xffff)), s2, a0) + b[4 * c + 0];
  a1 = fmaf(bf2f((ushort)(sv.x >> 16)), s2, a1) + b[4 * c + 1];
  a2 = fmaf(bf2f((ushort)(sv.y & 0xffff)), s2, a2) + b[4 * c + 2];
  a3 = fmaf(bf2f((ushort)(sv.y >> 16)), s2, a3) + b[4 * c + 3];
  float m = fmaxf(fmaxf(a0, a1), fmaxf(a2, a3));
  m = fmaxf(m, __shfl_xor(m, 1));
  m = fmaxf(m, __shfl_xor(m, 2));
  float ssum = expf(a0 - m) + expf(a1 - m) + expf(a2 - m) + expf(a3 - m);
  ssum += __shfl_xor(ssum, 1);
  ssum += __shfl_xor(ssum, 2);
  float l = m + logf(ssum);
  if (e == 0)
    *(float4*)(out + (size_t)node * DIM_OUT + c * 4) =
        make_float4(a0 - l, a1 - l, a2 - l, a3 - l);
}

// ======================= launch =======================

extern "C" void kernel_launch(void* const* d_in, const int* in_sizes, int n_in,
                              void* d_out, int out_size, void* d_ws, size_t ws_size,
                              hipStream_t stream) {
  const float* x  = (const float*)d_in[0];
  const int*   ei = (const int*)d_in[1];
  const float* W1 = (const float*)d_in[2];
  const float* b1 = (const float*)d_in[3];
  const float* W2 = (const float*)d_in[4];
  const float* b2 = (const float*)d_in[5];
  float* out = (float*)d_out;

  int n = in_sizes[0] / DIM_IN;  // 100000
  int E = in_sizes[1] / 2;       // 1600000
  const int* srcv = ei;
  const int* dstv = ei + E;
  int NB = (n + 255) >> NBSHIFT;       // 391
  int NC = (E + CHUNK - 1) / CHUNK;    // 196

  char* wsb = (char*)d_ws;
  int* degi      = (int*)wsb;   wsb += (size_t)n * 4;
  int* rowptr    = (int*)wsb;   wsb += (size_t)n * 4;
  float* dinv    = (float*)wsb; wsb += (size_t)n * 4;
  int* gbhist    = (int*)wsb;   wsb += 512 * 4;
  int* bbase     = (int*)wsb;   wsb += 512 * 4;
  int* chunkhist = (int*)wsb;   wsb += (size_t)256 * 512 * 4;
  int* cstart    = (int*)wsb;   wsb += (size_t)256 * 512 * 4;
  uint* esrc     = (uint*)wsb;  wsb += (size_t)E * 4;
  ushort* h1     = (ushort*)wsb; wsb += (size_t)n * DIM_H * 2;
  ushort* agg1   = (ushort*)wsb; wsb += (size_t)n * DIM_H * 2;
  ushort* h2     = (ushort*)wsb; wsb += (size_t)n * DIM_OUT * 2;
  // pairs (E uint = 6.4 MB) aliases agg1 (12.8 MB): dead before k_gather64 writes
  uint* pairs = (uint*)agg1;

  // ---- CSR build: one cooperative kernel ----
  {
    void* args[] = {(void*)&srcv, (void*)&dstv, (void*)&E, (void*)&n,
                    (void*)&NC,  (void*)&NB,   (void*)&chunkhist,
                    (void*)&cstart, (void*)&gbhist, (void*)&bbase,
                    (void*)&pairs, (void*)&degi, (void*)&dinv,
                    (void*)&rowptr, (void*)&esrc};
    hipLaunchCooperativeKernel((void*)k_csrbuild, dim3(NB), dim3(256), args, 0,
                               stream);
  }

  // ---- layer 1 ----
  k_gemm1m<<<512, 256, 0, stream>>>(x, W1, h1, n, (n + 15) / 16);
  k_gather64<<<(n + 3) / 4, 256, 0, stream>>>(h1, esrc, rowptr, degi, dinv, b1,
                                              agg1, n);

  // ---- layer 2 ----
  k_gemm2<<<(n + 255) / 256, 256, 0, stream>>>(agg1, W2, h2, n);
  k_gather16<<<(n + 15) / 16, 256, 0, stream>>>(h2, esrc, rowptr, degi, dinv, b2,
                                                out, n);
}

// Round 12
// 146.267 us; speedup vs baseline: 2.4937x; 2.4937x over previous
//
#include <hip/hip_runtime.h>
#include <math.h>

#define DIM_IN 128
#define DIM_H 64
#define DIM_OUT 16
#define NBSHIFT 8  // 256 nodes per bucket
#define CHUNK 8192

typedef __attribute__((ext_vector_type(8))) short bf16x8;
typedef __attribute__((ext_vector_type(4))) float f32x4;

__device__ __forceinline__ ushort f2bf(float f) {
  uint u = __float_as_uint(f);
  return (ushort)((u + 0x7FFF + ((u >> 16) & 1)) >> 16);
}
__device__ __forceinline__ float bf2f(ushort s) {
  return __uint_as_float(((uint)s) << 16);
}
__device__ __forceinline__ uint cvtpk(float lo, float hi) {
  uint r;
  asm("v_cvt_pk_bf16_f32 %0, %1, %2" : "=v"(r) : "v"(lo), "v"(hi));
  return r;
}

// ============ CSR build: per-chunk hist -> scans -> partition (atomic-free) ====

__global__ __launch_bounds__(256) void k_hist1(const int* __restrict__ dst, int E,
                                               int* __restrict__ chunkhist) {
  __shared__ int lh[512];
  int t = threadIdx.x;
  int c = blockIdx.x;
  lh[t] = 0;
  lh[t + 256] = 0;
  __syncthreads();
  int e0 = c * CHUNK;
  int e1 = min(E, e0 + CHUNK);
  for (int i = e0 + t; i < e1; i += 256) atomicAdd(&lh[dst[i] >> NBSHIFT], 1);
  __syncthreads();
  chunkhist[c * 512 + t] = lh[t];
  chunkhist[c * 512 + t + 256] = lh[t + 256];
}

__global__ __launch_bounds__(256) void k_scanc(const int* __restrict__ chunkhist,
                                               int NC, int* __restrict__ cstart,
                                               int* __restrict__ gbhist) {
  __shared__ int sc[256];
  int t = threadIdx.x;
  int b = blockIdx.x;
  int v = (t < NC) ? chunkhist[t * 512 + b] : 0;
  sc[t] = v;
  __syncthreads();
  for (int off = 1; off < 256; off <<= 1) {
    int add = (t >= off) ? sc[t - off] : 0;
    __syncthreads();
    sc[t] += add;
    __syncthreads();
  }
  if (t < NC) cstart[t * 512 + b] = sc[t] - v;
  if (t == 255) gbhist[b] = sc[255];
}

__global__ __launch_bounds__(512) void k_bscan(const int* __restrict__ gbhist,
                                               int* __restrict__ bbase) {
  __shared__ int sb[512];
  int t = threadIdx.x;
  int v = gbhist[t];
  sb[t] = v;
  __syncthreads();
  for (int off = 1; off < 512; off <<= 1) {
    int add = (t >= off) ? sb[t - off] : 0;
    __syncthreads();
    sb[t] += add;
    __syncthreads();
  }
  bbase[t] = sb[t] - v;
}

// pairs packed: (src << 8) | (dst & 255)
__global__ __launch_bounds__(256) void k_part2(const int* __restrict__ src,
                                               const int* __restrict__ dst, int E,
                                               const int* __restrict__ cstart,
                                               const int* __restrict__ bbase,
                                               uint* __restrict__ pairs) {
  __shared__ int lcur[512];
  int t = threadIdx.x;
  int c = blockIdx.x;
  lcur[t] = cstart[c * 512 + t] + bbase[t];
  lcur[t + 256] = cstart[c * 512 + t + 256] + bbase[t + 256];
  __syncthreads();
  int e0 = c * CHUNK;
  int e1 = min(E, e0 + CHUNK);
  for (int i = e0 + t; i < e1; i += 256) {
    int d = dst[i];
    int pos = atomicAdd(&lcur[d >> NBSHIFT], 1);
    pairs[pos] = ((uint)src[i] << 8) | ((uint)d & 255u);
  }
}

__global__ __launch_bounds__(256) void k_csr(const uint* __restrict__ pairs,
                                             const int* __restrict__ gbhist,
                                             const int* __restrict__ bbase, int n,
                                             int* __restrict__ degi,
                                             float* __restrict__ dinv,
                                             int* __restrict__ rowptr,
                                             int* __restrict__ srcs) {
  __shared__ int nh[256];
  __shared__ int ncur[256];
  int t = threadIdx.x;
  int b = blockIdx.x;
  int base = bbase[b];
  int cnt = gbhist[b];
  nh[t] = 0;
  __syncthreads();
  for (int i = t; i < cnt; i += 256) atomicAdd(&nh[pairs[base + i] & 255u], 1);
  __syncthreads();
  int node = (b << NBSHIFT) + t;
  int v = nh[t];
  if (node < n) {
    degi[node] = v;
    dinv[node] = rsqrtf((float)v + 1.0f);
  }
  __syncthreads();
  for (int off = 1; off < 256; off <<= 1) {
    int add = (t >= off) ? nh[t - off] : 0;
    __syncthreads();
    nh[t] += add;
    __syncthreads();
  }
  int excl = nh[t] - v;
  if (node < n) rowptr[node] = base + excl;
  ncur[t] = base + excl;
  __syncthreads();
  for (int i = t; i < cnt; i += 256) {
    uint p = pairs[base + i];
    int pos = atomicAdd(&ncur[p & 255u], 1);
    srcs[pos] = (int)(p >> 8);
  }
}

// esrc[i] = (bf16(dinv[srcs[i]]) << 17) | srcs[i]
// (dinv<=1 -> bf16 pattern <= 0x3F80 fits 14 bits; src < 2^17)
__global__ __launch_bounds__(256) void k_pack(const int* __restrict__ srcs,
                                              const float* __restrict__ dinv,
                                              uint* __restrict__ esrc, int E) {
  int i = blockIdx.x * 256 + threadIdx.x;
  if (i < E) {
    uint s = (uint)srcs[i];
    esrc[i] = ((uint)f2bf(dinv[s]) << 17) | s;
  }
}

// ======================= GEMM1 (MFMA bf16): h1 = x @ W1 =======================
__global__ __launch_bounds__(256, 4) void k_gemm1m(const float* __restrict__ x,
                                                   const float* __restrict__ W,
                                                   ushort* __restrict__ h, int n,
                                                   int nTiles) {
  const int t = threadIdx.x;
  const int lane = t & 63;
  const int wid = blockIdx.x * 4 + (t >> 6);
  const int nW = gridDim.x * 4;
  const int cc = lane & 15;
  const int kb = (lane >> 4) * 8;

  bf16x8 bfrag[4][4];
#pragma unroll
  for (int kc = 0; kc < 4; ++kc)
#pragma unroll
    for (int nt = 0; nt < 4; ++nt) {
      union { bf16x8 v; uint u[4]; } fb;
#pragma unroll
      for (int j = 0; j < 4; ++j) {
        float lo = W[(size_t)(kc * 32 + kb + 2 * j) * DIM_H + nt * 16 + cc];
        float hi = W[(size_t)(kc * 32 + kb + 2 * j + 1) * DIM_H + nt * 16 + cc];
        fb.u[j] = cvtpk(lo, hi);
      }
      bfrag[kc][nt] = fb.v;
    }

  for (int tile = wid; tile < nTiles; tile += nW) {
    int row0 = tile * 16;
    int ra = row0 + cc;
    if (ra > n - 1) ra = n - 1;
    const float* xp = x + (size_t)ra * DIM_IN;
    f32x4 acc[4] = {{0.f, 0.f, 0.f, 0.f},
                    {0.f, 0.f, 0.f, 0.f},
                    {0.f, 0.f, 0.f, 0.f},
                    {0.f, 0.f, 0.f, 0.f}};
#pragma unroll
    for (int kc = 0; kc < 4; ++kc) {
      float4 a0 = *(const float4*)(xp + kc * 32 + kb);
      float4 a1 = *(const float4*)(xp + kc * 32 + kb + 4);
      union { bf16x8 v; uint u[4]; } fa;
      fa.u[0] = cvtpk(a0.x, a0.y);
      fa.u[1] = cvtpk(a0.z, a0.w);
      fa.u[2] = cvtpk(a1.x, a1.y);
      fa.u[3] = cvtpk(a1.z, a1.w);
#pragma unroll
      for (int nt = 0; nt < 4; ++nt)
        acc[nt] = __builtin_amdgcn_mfma_f32_16x16x32_bf16(fa.v, bfrag[kc][nt],
                                                          acc[nt], 0, 0, 0);
    }
    int rbase = row0 + (lane >> 4) * 4;
#pragma unroll
    for (int nt = 0; nt < 4; ++nt) {
      int col = nt * 16 + cc;
#pragma unroll
      for (int j = 0; j < 4; ++j) {
        int r = rbase + j;
        if (r < n) h[(size_t)r * DIM_H + col] = f2bf(acc[nt][j]);
      }
    }
  }
}

// ============ GEMM2: h2(bf16) = agg1r(bf16, already relu'd) @ W2 ============
__global__ __launch_bounds__(256) void k_gemm2(const ushort* __restrict__ a,
                                               const float* __restrict__ W,
                                               ushort* __restrict__ h2, int n) {
  __shared__ float Ws[64][16];
  const int t = threadIdx.x;
  for (int i = t; i < 64 * 16; i += 256) Ws[i >> 4][i & 15] = W[i];
  __syncthreads();
  int r = blockIdx.x * 256 + t;
  if (r >= n) return;
  const uint4* ap = (const uint4*)(a + (size_t)r * DIM_H);
  float acc[16] = {};
#pragma unroll
  for (int k8 = 0; k8 < 8; ++k8) {
    uint4 v = ap[k8];
    uint w[4] = {v.x, v.y, v.z, v.w};
#pragma unroll
    for (int p = 0; p < 4; ++p) {
      float v0 = bf2f((ushort)(w[p] & 0xffff));
      float v1 = bf2f((ushort)(w[p] >> 16));
      int k = k8 * 8 + p * 2;
#pragma unroll
      for (int j = 0; j < 16; ++j) acc[j] = fmaf(v0, Ws[k][j], acc[j]);
#pragma unroll
      for (int j = 0; j < 16; ++j) acc[j] = fmaf(v1, Ws[k + 1][j], acc[j]);
    }
  }
  ushort4* hp = (ushort4*)(h2 + (size_t)r * DIM_OUT);
#pragma unroll
  for (int q = 0; q < 4; ++q) {
    ushort4 o;
    o.x = f2bf(acc[q * 4 + 0]);
    o.y = f2bf(acc[q * 4 + 1]);
    o.z = f2bf(acc[q * 4 + 2]);
    o.w = f2bf(acc[q * 4 + 3]);
    hp[q] = o;
  }
}

// ======================= gather aggregation =======================

// layer 1: one wave per node; q=lane&15 owns cols 4q..4q+3, g=lane>>4 walks
// edges j+g, j+4+g, j+8+g, j+12+g. esrc packed (weight bf16 | src). Output is
// relu(agg + self + bias) in bf16 (relu pre-applied for GEMM2).
__global__ __launch_bounds__(256) void k_gather64(const ushort* __restrict__ h,
                                                  const uint* __restrict__ esrc,
                                                  const int* __restrict__ rowptr,
                                                  const int* __restrict__ deg,
                                                  const float* __restrict__ dinv,
                                                  const float* __restrict__ b,
                                                  ushort* __restrict__ out, int n) {
  int node = blockIdx.x * 4 + (threadIdx.x >> 6);
  int lane = threadIdx.x & 63;
  int g = lane >> 4;
  int q = lane & 15;
  if (node >= n) return;
  int start = rowptr[node];
  int cnt = deg[node];
  float dd = dinv[node];
  float a0 = 0.f, a1 = 0.f, a2 = 0.f, a3 = 0.f;
  for (int j0 = 0; j0 < cnt; j0 += 64) {
    int rem = cnt - j0;
    if (rem > 64) rem = 64;
    uint p_l = (lane < rem) ? esrc[start + j0 + lane] : 0u;
    int s_l = (int)(p_l & 0x1FFFFu);
    float w_l = bf2f((ushort)(p_l >> 17)) * dd;  // 0 for padded lanes
    for (int j = 0; j < rem; j += 16) {
      int i0 = j + g, i1 = j + 4 + g, i2 = j + 8 + g, i3 = j + 12 + g;
      int s0 = __shfl(s_l, i0);
      float w0 = __shfl(w_l, i0);
      int s1 = __shfl(s_l, i1);
      float w1 = __shfl(w_l, i1);
      int s2 = __shfl(s_l, i2);
      float w2 = __shfl(w_l, i2);
      int s3 = __shfl(s_l, i3);
      float w3 = __shfl(w_l, i3);
      uint2 v0 = *(const uint2*)(h + (size_t)s0 * DIM_H + q * 4);
      uint2 v1 = *(const uint2*)(h + (size_t)s1 * DIM_H + q * 4);
      uint2 v2 = *(const uint2*)(h + (size_t)s2 * DIM_H + q * 4);
      uint2 v3 = *(const uint2*)(h + (size_t)s3 * DIM_H + q * 4);
      a0 = fmaf(bf2f((ushort)(v0.x & 0xffff)), w0, a0);
      a1 = fmaf(bf2f((ushort)(v0.x >> 16)), w0, a1);
      a2 = fmaf(bf2f((ushort)(v0.y & 0xffff)), w0, a2);
      a3 = fmaf(bf2f((ushort)(v0.y >> 16)), w0, a3);
      a0 = fmaf(bf2f((ushort)(v1.x & 0xffff)), w1, a0);
      a1 = fmaf(bf2f((ushort)(v1.x >> 16)), w1, a1);
      a2 = fmaf(bf2f((ushort)(v1.y & 0xffff)), w1, a2);
      a3 = fmaf(bf2f((ushort)(v1.y >> 16)), w1, a3);
      a0 = fmaf(bf2f((ushort)(v2.x & 0xffff)), w2, a0);
      a1 = fmaf(bf2f((ushort)(v2.x >> 16)), w2, a1);
      a2 = fmaf(bf2f((ushort)(v2.y & 0xffff)), w2, a2);
      a3 = fmaf(bf2f((ushort)(v2.y >> 16)), w2, a3);
      a0 = fmaf(bf2f((ushort)(v3.x & 0xffff)), w3, a0);
      a1 = fmaf(bf2f((ushort)(v3.x >> 16)), w3, a1);
      a2 = fmaf(bf2f((ushort)(v3.y & 0xffff)), w3, a2);
      a3 = fmaf(bf2f((ushort)(v3.y >> 16)), w3, a3);
    }
  }
  a0 += __shfl_xor(a0, 16); a0 += __shfl_xor(a0, 32);
  a1 += __shfl_xor(a1, 16); a1 += __shfl_xor(a1, 32);
  a2 += __shfl_xor(a2, 16); a2 += __shfl_xor(a2, 32);
  a3 += __shfl_xor(a3, 16); a3 += __shfl_xor(a3, 32);
  if (g == 0) {
    uint2 sv = *(const uint2*)(h + (size_t)node * DIM_H + q * 4);
    float s2 = dd * dd;
    a0 = fmaxf(fmaf(bf2f((ushort)(sv.x & 0xffff)), s2, a0) + b[4 * q + 0], 0.f);
    a1 = fmaxf(fmaf(bf2f((ushort)(sv.x >> 16)), s2, a1) + b[4 * q + 1], 0.f);
    a2 = fmaxf(fmaf(bf2f((ushort)(sv.y & 0xffff)), s2, a2) + b[4 * q + 2], 0.f);
    a3 = fmaxf(fmaf(bf2f((ushort)(sv.y >> 16)), s2, a3) + b[4 * q + 3], 0.f);
    uint lo = cvtpk(a0, a1);
    uint hi = cvtpk(a2, a3);
    *(uint2*)(out + (size_t)node * DIM_H + q * 4) = make_uint2(lo, hi);
  }
}

// layer 2: 16 lanes per node; c=lane&3 owns cols 4c..4c+3, e=(lane>>2)&3 picks
// edges e,4+e,8+e,12+e. esrc packed. Fused self+bias+log_softmax. out f32.
__global__ __launch_bounds__(256) void k_gather16(const ushort* __restrict__ h,
                                                  const uint* __restrict__ esrc,
                                                  const int* __restrict__ rowptr,
                                                  const int* __restrict__ deg,
                                                  const float* __restrict__ dinv,
                                                  const float* __restrict__ b,
                                                  float* __restrict__ out, int n) {
  int node = blockIdx.x * 16 + (threadIdx.x >> 4);
  int lane = threadIdx.x & 63;
  int lane16 = lane & 15;
  int gbase = lane & 48;
  int e = (lane >> 2) & 3;
  int c = lane & 3;
  if (node >= n) return;
  int start = rowptr[node];
  int cnt = deg[node];
  float dd = dinv[node];
  const int iA = gbase + e, iB = gbase + 4 + e, iC = gbase + 8 + e,
            iD = gbase + 12 + e;
  float a0 = 0.f, a1 = 0.f, a2 = 0.f, a3 = 0.f;
  for (int j0 = 0; j0 < cnt; j0 += 16) {
    int rem = cnt - j0;
    if (rem > 16) rem = 16;
    uint p_l = (lane16 < rem) ? esrc[start + j0 + lane16] : 0u;
    int s_l = (int)(p_l & 0x1FFFFu);
    float w_l = bf2f((ushort)(p_l >> 17)) * dd;
    int sA = __shfl(s_l, iA);
    float wA = __shfl(w_l, iA);
    int sB = __shfl(s_l, iB);
    float wB = __shfl(w_l, iB);
    int sC = __shfl(s_l, iC);
    float wC = __shfl(w_l, iC);
    int sD = __shfl(s_l, iD);
    float wD = __shfl(w_l, iD);
    uint2 vA = *(const uint2*)(h + (size_t)sA * DIM_OUT + c * 4);
    uint2 vB = *(const uint2*)(h + (size_t)sB * DIM_OUT + c * 4);
    uint2 vC = *(const uint2*)(h + (size_t)sC * DIM_OUT + c * 4);
    uint2 vD = *(const uint2*)(h + (size_t)sD * DIM_OUT + c * 4);
    a0 = fmaf(bf2f((ushort)(vA.x & 0xffff)), wA, a0);
    a1 = fmaf(bf2f((ushort)(vA.x >> 16)), wA, a1);
    a2 = fmaf(bf2f((ushort)(vA.y & 0xffff)), wA, a2);
    a3 = fmaf(bf2f((ushort)(vA.y >> 16)), wA, a3);
    a0 = fmaf(bf2f((ushort)(vB.x & 0xffff)), wB, a0);
    a1 = fmaf(bf2f((ushort)(vB.x >> 16)), wB, a1);
    a2 = fmaf(bf2f((ushort)(vB.y & 0xffff)), wB, a2);
    a3 = fmaf(bf2f((ushort)(vB.y >> 16)), wB, a3);
    a0 = fmaf(bf2f((ushort)(vC.x & 0xffff)), wC, a0);
    a1 = fmaf(bf2f((ushort)(vC.x >> 16)), wC, a1);
    a2 = fmaf(bf2f((ushort)(vC.y & 0xffff)), wC, a2);
    a3 = fmaf(bf2f((ushort)(vC.y >> 16)), wC, a3);
    a0 = fmaf(bf2f((ushort)(vD.x & 0xffff)), wD, a0);
    a1 = fmaf(bf2f((ushort)(vD.x >> 16)), wD, a1);
    a2 = fmaf(bf2f((ushort)(vD.y & 0xffff)), wD, a2);
    a3 = fmaf(bf2f((ushort)(vD.y >> 16)), wD, a3);
  }
  a0 += __shfl_xor(a0, 4); a0 += __shfl_xor(a0, 8);
  a1 += __shfl_xor(a1, 4); a1 += __shfl_xor(a1, 8);
  a2 += __shfl_xor(a2, 4); a2 += __shfl_xor(a2, 8);
  a3 += __shfl_xor(a3, 4); a3 += __shfl_xor(a3, 8);
  uint2 sv = *(const uint2*)(h + (size_t)node * DIM_OUT + c * 4);
  float s2 = dd * dd;
  a0 = fmaf(bf2f((ushort)(sv.x & 0xffff)), s2, a0) + b[4 * c + 0];
  a1 = fmaf(bf2f((ushort)(sv.x >> 16)), s2, a1) + b[4 * c + 1];
  a2 = fmaf(bf2f((ushort)(sv.y & 0xffff)), s2, a2) + b[4 * c + 2];
  a3 = fmaf(bf2f((ushort)(sv.y >> 16)), s2, a3) + b[4 * c + 3];
  float m = fmaxf(fmaxf(a0, a1), fmaxf(a2, a3));
  m = fmaxf(m, __shfl_xor(m, 1));
  m = fmaxf(m, __shfl_xor(m, 2));
  float ssum = expf(a0 - m) + expf(a1 - m) + expf(a2 - m) + expf(a3 - m);
  ssum += __shfl_xor(ssum, 1);
  ssum += __shfl_xor(ssum, 2);
  float l = m + logf(ssum);
  if (e == 0)
    *(float4*)(out + (size_t)node * DIM_OUT + c * 4) =
        make_float4(a0 - l, a1 - l, a2 - l, a3 - l);
}

// ======================= launch =======================

extern "C" void kernel_launch(void* const* d_in, const int* in_sizes, int n_in,
                              void* d_out, int out_size, void* d_ws, size_t ws_size,
                              hipStream_t stream) {
  const float* x  = (const float*)d_in[0];
  const int*   ei = (const int*)d_in[1];
  const float* W1 = (const float*)d_in[2];
  const float* b1 = (const float*)d_in[3];
  const float* W2 = (const float*)d_in[4];
  const float* b2 = (const float*)d_in[5];
  float* out = (float*)d_out;

  const int n = in_sizes[0] / DIM_IN;  // 100000
  const int E = in_sizes[1] / 2;       // 1600000
  const int* srcv = ei;
  const int* dstv = ei + E;
  const int NB = (n + 255) >> NBSHIFT;     // 391
  const int NC = (E + CHUNK - 1) / CHUNK;  // 196 (<=256)

  char* wsb = (char*)d_ws;
  int* degi      = (int*)wsb;   wsb += (size_t)n * 4;
  int* rowptr    = (int*)wsb;   wsb += (size_t)n * 4;
  float* dinv    = (float*)wsb; wsb += (size_t)n * 4;
  int* gbhist    = (int*)wsb;   wsb += 512 * 4;
  int* bbase     = (int*)wsb;   wsb += 512 * 4;
  int* chunkhist = (int*)wsb;   wsb += (size_t)256 * 512 * 4;
  int* cstart    = (int*)wsb;   wsb += (size_t)256 * 512 * 4;
  int* srcs      = (int*)wsb;   wsb += (size_t)E * 4;
  uint* esrc     = (uint*)wsb;  wsb += (size_t)E * 4;
  ushort* h1     = (ushort*)wsb; wsb += (size_t)n * DIM_H * 2;
  ushort* agg1   = (ushort*)wsb; wsb += (size_t)n * DIM_H * 2;
  ushort* h2     = (ushort*)wsb; wsb += (size_t)n * DIM_OUT * 2;
  // pairs (E uint = 6.4 MB) aliases agg1 (12.8 MB): dead before k_gather64 writes
  uint* pairs = (uint*)agg1;

  // ---- CSR build (deterministic, separate kernels) ----
  k_hist1<<<NC, 256, 0, stream>>>(dstv, E, chunkhist);
  k_scanc<<<512, 256, 0, stream>>>(chunkhist, NC, cstart, gbhist);
  k_bscan<<<1, 512, 0, stream>>>(gbhist, bbase);
  k_part2<<<NC, 256, 0, stream>>>(srcv, dstv, E, cstart, bbase, pairs);
  k_csr<<<NB, 256, 0, stream>>>(pairs, gbhist, bbase, n, degi, dinv, rowptr, srcs);
  k_pack<<<(E + 255) / 256, 256, 0, stream>>>(srcs, dinv, esrc, E);

  // ---- layer 1 ----
  k_gemm1m<<<512, 256, 0, stream>>>(x, W1, h1, n, (n + 15) / 16);
  k_gather64<<<(n + 3) / 4, 256, 0, stream>>>(h1, esrc, rowptr, degi, dinv, b1,
                                              agg1, n);

  // ---- layer 2 ----
  k_gemm2<<<(n + 255) / 256, 256, 0, stream>>>(agg1, W2, h2, n);
  k_gather16<<<(n + 15) / 16, 256, 0, stream>>>(h2, esrc, rowptr, degi, dinv, b2,
                                                out, n);
}

// Round 13
// 141.037 us; speedup vs baseline: 2.5862x; 1.0371x over previous
//
#include <hip/hip_runtime.h>
#include <math.h>

#define DIM_IN 128
#define DIM_H 64
#define DIM_OUT 16
#define NBSHIFT 8  // 256 nodes per bucket
#define CHUNK 8192

typedef __attribute__((ext_vector_type(8))) short bf16x8;
typedef __attribute__((ext_vector_type(4))) float f32x4;
typedef __attribute__((ext_vector_type(2))) float f32x2;

__device__ __forceinline__ ushort f2bf(float f) {
  uint u = __float_as_uint(f);
  return (ushort)((u + 0x7FFF + ((u >> 16) & 1)) >> 16);
}
__device__ __forceinline__ float bf2f(ushort s) {
  return __uint_as_float(((uint)s) << 16);
}
__device__ __forceinline__ uint cvtpk(float lo, float hi) {
  uint r;
  asm("v_cvt_pk_bf16_f32 %0, %1, %2" : "=v"(r) : "v"(lo), "v"(hi));
  return r;
}
// 2x f32 -> 2x fp8(e4m3 on gfx950) in [15:0]
__device__ __forceinline__ uint f2fp8pk(float a, float b) {
  uint r = 0;
  asm("v_cvt_pk_fp8_f32 %0, %1, %2" : "+v"(r) : "v"(a), "v"(b));
  return r & 0xffffu;
}
// decode 2x fp8 from u[15:0]
__device__ __forceinline__ f32x2 fp8pk2f(uint u) {
  f32x2 r;
  asm("v_cvt_pk_f32_fp8 %0, %1" : "=v"(r) : "v"(u));
  return r;
}

// ============ CSR build: per-chunk hist -> scans -> partition (atomic-free) ====

__global__ __launch_bounds__(256) void k_hist1(const int* __restrict__ dst, int E,
                                               int* __restrict__ chunkhist) {
  __shared__ int lh[512];
  int t = threadIdx.x;
  int c = blockIdx.x;
  lh[t] = 0;
  lh[t + 256] = 0;
  __syncthreads();
  int e0 = c * CHUNK;
  int e1 = min(E, e0 + CHUNK);
  for (int i = e0 + t; i < e1; i += 256) atomicAdd(&lh[dst[i] >> NBSHIFT], 1);
  __syncthreads();
  chunkhist[c * 512 + t] = lh[t];
  chunkhist[c * 512 + t + 256] = lh[t + 256];
}

__global__ __launch_bounds__(256) void k_scanc(const int* __restrict__ chunkhist,
                                               int NC, int* __restrict__ cstart,
                                               int* __restrict__ gbhist) {
  __shared__ int sc[256];
  int t = threadIdx.x;
  int b = blockIdx.x;
  int v = (t < NC) ? chunkhist[t * 512 + b] : 0;
  sc[t] = v;
  __syncthreads();
  for (int off = 1; off < 256; off <<= 1) {
    int add = (t >= off) ? sc[t - off] : 0;
    __syncthreads();
    sc[t] += add;
    __syncthreads();
  }
  if (t < NC) cstart[t * 512 + b] = sc[t] - v;
  if (t == 255) gbhist[b] = sc[255];
}

__global__ __launch_bounds__(512) void k_bscan(const int* __restrict__ gbhist,
                                               int* __restrict__ bbase) {
  __shared__ int sb[512];
  int t = threadIdx.x;
  int v = gbhist[t];
  sb[t] = v;
  __syncthreads();
  for (int off = 1; off < 512; off <<= 1) {
    int add = (t >= off) ? sb[t - off] : 0;
    __syncthreads();
    sb[t] += add;
    __syncthreads();
  }
  bbase[t] = sb[t] - v;
}

// pairs packed: (src << 8) | (dst & 255)
__global__ __launch_bounds__(256) void k_part2(const int* __restrict__ src,
                                               const int* __restrict__ dst, int E,
                                               const int* __restrict__ cstart,
                                               const int* __restrict__ bbase,
                                               uint* __restrict__ pairs) {
  __shared__ int lcur[512];
  int t = threadIdx.x;
  int c = blockIdx.x;
  lcur[t] = cstart[c * 512 + t] + bbase[t];
  lcur[t + 256] = cstart[c * 512 + t + 256] + bbase[t + 256];
  __syncthreads();
  int e0 = c * CHUNK;
  int e1 = min(E, e0 + CHUNK);
  for (int i = e0 + t; i < e1; i += 256) {
    int d = dst[i];
    int pos = atomicAdd(&lcur[d >> NBSHIFT], 1);
    pairs[pos] = ((uint)src[i] << 8) | ((uint)d & 255u);
  }
}

__global__ __launch_bounds__(256) void k_csr(const uint* __restrict__ pairs,
                                             const int* __restrict__ gbhist,
                                             const int* __restrict__ bbase, int n,
                                             int* __restrict__ degi,
                                             float* __restrict__ dinv,
                                             int* __restrict__ rowptr,
                                             int* __restrict__ srcs) {
  __shared__ int nh[256];
  __shared__ int ncur[256];
  int t = threadIdx.x;
  int b = blockIdx.x;
  int base = bbase[b];
  int cnt = gbhist[b];
  nh[t] = 0;
  __syncthreads();
  for (int i = t; i < cnt; i += 256) atomicAdd(&nh[pairs[base + i] & 255u], 1);
  __syncthreads();
  int node = (b << NBSHIFT) + t;
  int v = nh[t];
  if (node < n) {
    degi[node] = v;
    dinv[node] = rsqrtf((float)v + 1.0f);
  }
  __syncthreads();
  for (int off = 1; off < 256; off <<= 1) {
    int add = (t >= off) ? nh[t - off] : 0;
    __syncthreads();
    nh[t] += add;
    __syncthreads();
  }
  int excl = nh[t] - v;
  if (node < n) rowptr[node] = base + excl;
  ncur[t] = base + excl;
  __syncthreads();
  for (int i = t; i < cnt; i += 256) {
    uint p = pairs[base + i];
    int pos = atomicAdd(&ncur[p & 255u], 1);
    srcs[pos] = (int)(p >> 8);
  }
}

// esrc[i] = (bf16(dinv[srcs[i]]) << 17) | srcs[i]
__global__ __launch_bounds__(256) void k_pack(const int* __restrict__ srcs,
                                              const float* __restrict__ dinv,
                                              uint* __restrict__ esrc, int E) {
  int i = blockIdx.x * 256 + threadIdx.x;
  if (i < E) {
    uint s = (uint)srcs[i];
    esrc[i] = ((uint)f2bf(dinv[s]) << 17) | s;
  }
}

// ============== GEMM1 (MFMA bf16): h1(fp8 e4m3) = x @ W1 ==============
__global__ __launch_bounds__(256, 4) void k_gemm1m(const float* __restrict__ x,
                                                   const float* __restrict__ W,
                                                   uchar* __restrict__ h, int n,
                                                   int nTiles) {
  const int t = threadIdx.x;
  const int lane = t & 63;
  const int wid = blockIdx.x * 4 + (t >> 6);
  const int nW = gridDim.x * 4;
  const int cc = lane & 15;
  const int kb = (lane >> 4) * 8;

  bf16x8 bfrag[4][4];
#pragma unroll
  for (int kc = 0; kc < 4; ++kc)
#pragma unroll
    for (int nt = 0; nt < 4; ++nt) {
      union { bf16x8 v; uint u[4]; } fb;
#pragma unroll
      for (int j = 0; j < 4; ++j) {
        float lo = W[(size_t)(kc * 32 + kb + 2 * j) * DIM_H + nt * 16 + cc];
        float hi = W[(size_t)(kc * 32 + kb + 2 * j + 1) * DIM_H + nt * 16 + cc];
        fb.u[j] = cvtpk(lo, hi);
      }
      bfrag[kc][nt] = fb.v;
    }

  for (int tile = wid; tile < nTiles; tile += nW) {
    int row0 = tile * 16;
    int ra = row0 + cc;
    if (ra > n - 1) ra = n - 1;
    const float* xp = x + (size_t)ra * DIM_IN;
    f32x4 acc[4] = {{0.f, 0.f, 0.f, 0.f},
                    {0.f, 0.f, 0.f, 0.f},
                    {0.f, 0.f, 0.f, 0.f},
                    {0.f, 0.f, 0.f, 0.f}};
#pragma unroll
    for (int kc = 0; kc < 4; ++kc) {
      float4 a0 = *(const float4*)(xp + kc * 32 + kb);
      float4 a1 = *(const float4*)(xp + kc * 32 + kb + 4);
      union { bf16x8 v; uint u[4]; } fa;
      fa.u[0] = cvtpk(a0.x, a0.y);
      fa.u[1] = cvtpk(a0.z, a0.w);
      fa.u[2] = cvtpk(a1.x, a1.y);
      fa.u[3] = cvtpk(a1.z, a1.w);
#pragma unroll
      for (int nt = 0; nt < 4; ++nt)
        acc[nt] = __builtin_amdgcn_mfma_f32_16x16x32_bf16(fa.v, bfrag[kc][nt],
                                                          acc[nt], 0, 0, 0);
    }
    int rbase = row0 + (lane >> 4) * 4;
#pragma unroll
    for (int nt = 0; nt < 4; ++nt) {
      int col = nt * 16 + cc;
      uint w01 = f2fp8pk(acc[nt][0], acc[nt][1]);
      uint w23 = f2fp8pk(acc[nt][2], acc[nt][3]);
      uchar bytes[4] = {(uchar)(w01 & 0xff), (uchar)(w01 >> 8),
                        (uchar)(w23 & 0xff), (uchar)(w23 >> 8)};
#pragma unroll
      for (int j = 0; j < 4; ++j) {
        int r = rbase + j;
        if (r < n) h[(size_t)r * DIM_H + col] = bytes[j];
      }
    }
  }
}

// ============ GEMM2: h2(bf16) = agg1r(bf16, already relu'd) @ W2 ============
__global__ __launch_bounds__(256) void k_gemm2(const ushort* __restrict__ a,
                                               const float* __restrict__ W,
                                               ushort* __restrict__ h2, int n) {
  __shared__ float Ws[64][16];
  const int t = threadIdx.x;
  for (int i = t; i < 64 * 16; i += 256) Ws[i >> 4][i & 15] = W[i];
  __syncthreads();
  int r = blockIdx.x * 256 + t;
  if (r >= n) return;
  const uint4* ap = (const uint4*)(a + (size_t)r * DIM_H);
  float acc[16] = {};
#pragma unroll
  for (int k8 = 0; k8 < 8; ++k8) {
    uint4 v = ap[k8];
    uint w[4] = {v.x, v.y, v.z, v.w};
#pragma unroll
    for (int p = 0; p < 4; ++p) {
      float v0 = bf2f((ushort)(w[p] & 0xffff));
      float v1 = bf2f((ushort)(w[p] >> 16));
      int k = k8 * 8 + p * 2;
#pragma unroll
      for (int j = 0; j < 16; ++j) acc[j] = fmaf(v0, Ws[k][j], acc[j]);
#pragma unroll
      for (int j = 0; j < 16; ++j) acc[j] = fmaf(v1, Ws[k + 1][j], acc[j]);
    }
  }
  ushort4* hp = (ushort4*)(h2 + (size_t)r * DIM_OUT);
#pragma unroll
  for (int q = 0; q < 4; ++q) {
    ushort4 o;
    o.x = f2bf(acc[q * 4 + 0]);
    o.y = f2bf(acc[q * 4 + 1]);
    o.z = f2bf(acc[q * 4 + 2]);
    o.w = f2bf(acc[q * 4 + 3]);
    hp[q] = o;
  }
}

// ======================= gather aggregation =======================

// layer 1: one wave per node; q=lane&15 owns cols 4q..4q+3 (uint = 4 fp8),
// g=lane>>4 walks edges j+g, j+4+g, j+8+g, j+12+g. esrc packed. Output is
// relu(agg + self + bias) in bf16.
__global__ __launch_bounds__(256) void k_gather64(const uchar* __restrict__ h,
                                                  const uint* __restrict__ esrc,
                                                  const int* __restrict__ rowptr,
                                                  const int* __restrict__ deg,
                                                  const float* __restrict__ dinv,
                                                  const float* __restrict__ b,
                                                  ushort* __restrict__ out, int n) {
  int node = blockIdx.x * 4 + (threadIdx.x >> 6);
  int lane = threadIdx.x & 63;
  int g = lane >> 4;
  int q = lane & 15;
  if (node >= n) return;
  int start = rowptr[node];
  int cnt = deg[node];
  float dd = dinv[node];
  float a0 = 0.f, a1 = 0.f, a2 = 0.f, a3 = 0.f;
  for (int j0 = 0; j0 < cnt; j0 += 64) {
    int rem = cnt - j0;
    if (rem > 64) rem = 64;
    uint p_l = (lane < rem) ? esrc[start + j0 + lane] : 0u;
    int s_l = (int)(p_l & 0x1FFFFu);
    float w_l = bf2f((ushort)(p_l >> 17)) * dd;  // 0 for padded lanes
    for (int j = 0; j < rem; j += 16) {
      int i0 = j + g, i1 = j + 4 + g, i2 = j + 8 + g, i3 = j + 12 + g;
      int s0 = __shfl(s_l, i0);
      float w0 = __shfl(w_l, i0);
      int s1 = __shfl(s_l, i1);
      float w1 = __shfl(w_l, i1);
      int s2 = __shfl(s_l, i2);
      float w2 = __shfl(w_l, i2);
      int s3 = __shfl(s_l, i3);
      float w3 = __shfl(w_l, i3);
      uint v0 = *(const uint*)(h + (size_t)s0 * DIM_H + q * 4);
      uint v1 = *(const uint*)(h + (size_t)s1 * DIM_H + q * 4);
      uint v2 = *(const uint*)(h + (size_t)s2 * DIM_H + q * 4);
      uint v3 = *(const uint*)(h + (size_t)s3 * DIM_H + q * 4);
      f32x2 l0 = fp8pk2f(v0), h0 = fp8pk2f(v0 >> 16);
      f32x2 l1 = fp8pk2f(v1), h1v = fp8pk2f(v1 >> 16);
      f32x2 l2 = fp8pk2f(v2), h2v = fp8pk2f(v2 >> 16);
      f32x2 l3 = fp8pk2f(v3), h3v = fp8pk2f(v3 >> 16);
      a0 = fmaf(l0.x, w0, a0);
      a1 = fmaf(l0.y, w0, a1);
      a2 = fmaf(h0.x, w0, a2);
      a3 = fmaf(h0.y, w0, a3);
      a0 = fmaf(l1.x, w1, a0);
      a1 = fmaf(l1.y, w1, a1);
      a2 = fmaf(h1v.x, w1, a2);
      a3 = fmaf(h1v.y, w1, a3);
      a0 = fmaf(l2.x, w2, a0);
      a1 = fmaf(l2.y, w2, a1);
      a2 = fmaf(h2v.x, w2, a2);
      a3 = fmaf(h2v.y, w2, a3);
      a0 = fmaf(l3.x, w3, a0);
      a1 = fmaf(l3.y, w3, a1);
      a2 = fmaf(h3v.x, w3, a2);
      a3 = fmaf(h3v.y, w3, a3);
    }
  }
  a0 += __shfl_xor(a0, 16); a0 += __shfl_xor(a0, 32);
  a1 += __shfl_xor(a1, 16); a1 += __shfl_xor(a1, 32);
  a2 += __shfl_xor(a2, 16); a2 += __shfl_xor(a2, 32);
  a3 += __shfl_xor(a3, 16); a3 += __shfl_xor(a3, 32);
  if (g == 0) {
    uint sv = *(const uint*)(h + (size_t)node * DIM_H + q * 4);
    f32x2 slo = fp8pk2f(sv), shi = fp8pk2f(sv >> 16);
    float s2 = dd * dd;
    a0 = fmaxf(fmaf(slo.x, s2, a0) + b[4 * q + 0], 0.f);
    a1 = fmaxf(fmaf(slo.y, s2, a1) + b[4 * q + 1], 0.f);
    a2 = fmaxf(fmaf(shi.x, s2, a2) + b[4 * q + 2], 0.f);
    a3 = fmaxf(fmaf(shi.y, s2, a3) + b[4 * q + 3], 0.f);
    uint lo = cvtpk(a0, a1);
    uint hi = cvtpk(a2, a3);
    *(uint2*)(out + (size_t)node * DIM_H + q * 4) = make_uint2(lo, hi);
  }
}

// layer 2: 16 lanes per node; c=lane&3 owns cols 4c..4c+3, e=(lane>>2)&3 picks
// edges e,4+e,8+e,12+e. esrc packed. Fused self+bias+log_softmax. out f32.
__global__ __launch_bounds__(256) void k_gather16(const ushort* __restrict__ h,
                                                  const uint* __restrict__ esrc,
                                                  const int* __restrict__ rowptr,
                                                  const int* __restrict__ deg,
                                                  const float* __restrict__ dinv,
                                                  const float* __restrict__ b,
                                                  float* __restrict__ out, int n) {
  int node = blockIdx.x * 16 + (threadIdx.x >> 4);
  int lane = threadIdx.x & 63;
  int lane16 = lane & 15;
  int gbase = lane & 48;
  int e = (lane >> 2) & 3;
  int c = lane & 3;
  if (node >= n) return;
  int start = rowptr[node];
  int cnt = deg[node];
  float dd = dinv[node];
  const int iA = gbase + e, iB = gbase + 4 + e, iC = gbase + 8 + e,
            iD = gbase + 12 + e;
  float a0 = 0.f, a1 = 0.f, a2 = 0.f, a3 = 0.f;
  for (int j0 = 0; j0 < cnt; j0 += 16) {
    int rem = cnt - j0;
    if (rem > 16) rem = 16;
    uint p_l = (lane16 < rem) ? esrc[start + j0 + lane16] : 0u;
    int s_l = (int)(p_l & 0x1FFFFu);
    float w_l = bf2f((ushort)(p_l >> 17)) * dd;
    int sA = __shfl(s_l, iA);
    float wA = __shfl(w_l, iA);
    int sB = __shfl(s_l, iB);
    float wB = __shfl(w_l, iB);
    int sC = __shfl(s_l, iC);
    float wC = __shfl(w_l, iC);
    int sD = __shfl(s_l, iD);
    float wD = __shfl(w_l, iD);
    uint2 vA = *(const uint2*)(h + (size_t)sA * DIM_OUT + c * 4);
    uint2 vB = *(const uint2*)(h + (size_t)sB * DIM_OUT + c * 4);
    uint2 vC = *(const uint2*)(h + (size_t)sC * DIM_OUT + c * 4);
    uint2 vD = *(const uint2*)(h + (size_t)sD * DIM_OUT + c * 4);
    a0 = fmaf(bf2f((ushort)(vA.x & 0xffff)), wA, a0);
    a1 = fmaf(bf2f((ushort)(vA.x >> 16)), wA, a1);
    a2 = fmaf(bf2f((ushort)(vA.y & 0xffff)), wA, a2);
    a3 = fmaf(bf2f((ushort)(vA.y >> 16)), wA, a3);
    a0 = fmaf(bf2f((ushort)(vB.x & 0xffff)), wB, a0);
    a1 = fmaf(bf2f((ushort)(vB.x >> 16)), wB, a1);
    a2 = fmaf(bf2f((ushort)(vB.y & 0xffff)), wB, a2);
    a3 = fmaf(bf2f((ushort)(vB.y >> 16)), wB, a3);
    a0 = fmaf(bf2f((ushort)(vC.x & 0xffff)), wC, a0);
    a1 = fmaf(bf2f((ushort)(vC.x >> 16)), wC, a1);
    a2 = fmaf(bf2f((ushort)(vC.y & 0xffff)), wC, a2);
    a3 = fmaf(bf2f((ushort)(vC.y >> 16)), wC, a3);
    a0 = fmaf(bf2f((ushort)(vD.x & 0xffff)), wD, a0);
    a1 = fmaf(bf2f((ushort)(vD.x >> 16)), wD, a1);
    a2 = fmaf(bf2f((ushort)(vD.y & 0xffff)), wD, a2);
    a3 = fmaf(bf2f((ushort)(vD.y >> 16)), wD, a3);
  }
  a0 += __shfl_xor(a0, 4); a0 += __shfl_xor(a0, 8);
  a1 += __shfl_xor(a1, 4); a1 += __shfl_xor(a1, 8);
  a2 += __shfl_xor(a2, 4); a2 += __shfl_xor(a2, 8);
  a3 += __shfl_xor(a3, 4); a3 += __shfl_xor(a3, 8);
  uint2 sv = *(const uint2*)(h + (size_t)node * DIM_OUT + c * 4);
  float s2 = dd * dd;
  a0 = fmaf(bf2f((ushort)(sv.x & 0xffff)), s2, a0) + b[4 * c + 0];
  a1 = fmaf(bf2f((ushort)(sv.x >> 16)), s2, a1) + b[4 * c + 1];
  a2 = fmaf(bf2f((ushort)(sv.y & 0xffff)), s2, a2) + b[4 * c + 2];
  a3 = fmaf(bf2f((ushort)(sv.y >> 16)), s2, a3) + b[4 * c + 3];
  float m = fmaxf(fmaxf(a0, a1), fmaxf(a2, a3));
  m = fmaxf(m, __shfl_xor(m, 1));
  m = fmaxf(m, __shfl_xor(m, 2));
  float ssum = expf(a0 - m) + expf(a1 - m) + expf(a2 - m) + expf(a3 - m);
  ssum += __shfl_xor(ssum, 1);
  ssum += __shfl_xor(ssum, 2);
  float l = m + logf(ssum);
  if (e == 0)
    *(float4*)(out + (size_t)node * DIM_OUT + c * 4) =
        make_float4(a0 - l, a1 - l, a2 - l, a3 - l);
}

// ======================= launch =======================

extern "C" void kernel_launch(void* const* d_in, const int* in_sizes, int n_in,
                              void* d_out, int out_size, void* d_ws, size_t ws_size,
                              hipStream_t stream) {
  const float* x  = (const float*)d_in[0];
  const int*   ei = (const int*)d_in[1];
  const float* W1 = (const float*)d_in[2];
  const float* b1 = (const float*)d_in[3];
  const float* W2 = (const float*)d_in[4];
  const float* b2 = (const float*)d_in[5];
  float* out = (float*)d_out;

  const int n = in_sizes[0] / DIM_IN;  // 100000
  const int E = in_sizes[1] / 2;       // 1600000
  const int* srcv = ei;
  const int* dstv = ei + E;
  const int NB = (n + 255) >> NBSHIFT;     // 391
  const int NC = (E + CHUNK - 1) / CHUNK;  // 196 (<=256)

  char* wsb = (char*)d_ws;
  int* degi      = (int*)wsb;   wsb += (size_t)n * 4;
  int* rowptr    = (int*)wsb;   wsb += (size_t)n * 4;
  float* dinv    = (float*)wsb; wsb += (size_t)n * 4;
  int* gbhist    = (int*)wsb;   wsb += 512 * 4;
  int* bbase     = (int*)wsb;   wsb += 512 * 4;
  int* chunkhist = (int*)wsb;   wsb += (size_t)256 * 512 * 4;
  int* cstart    = (int*)wsb;   wsb += (size_t)256 * 512 * 4;
  int* srcs      = (int*)wsb;   wsb += (size_t)E * 4;
  uint* esrc     = (uint*)wsb;  wsb += (size_t)E * 4;
  uchar* h1      = (uchar*)wsb; wsb += (size_t)n * DIM_H;      // fp8
  ushort* agg1   = (ushort*)wsb; wsb += (size_t)n * DIM_H * 2;  // bf16
  ushort* h2     = (ushort*)wsb; wsb += (size_t)n * DIM_OUT * 2;
  // pairs (E uint = 6.4 MB) aliases agg1 (12.8 MB): dead before k_gather64 writes
  uint* pairs = (uint*)agg1;

  // ---- CSR build (deterministic, separate kernels) ----
  k_hist1<<<NC, 256, 0, stream>>>(dstv, E, chunkhist);
  k_scanc<<<512, 256, 0, stream>>>(chunkhist, NC, cstart, gbhist);
  k_bscan<<<1, 512, 0, stream>>>(gbhist, bbase);
  k_part2<<<NC, 256, 0, stream>>>(srcv, dstv, E, cstart, bbase, pairs);
  k_csr<<<NB, 256, 0, stream>>>(pairs, gbhist, bbase, n, degi, dinv, rowptr, srcs);
  k_pack<<<(E + 255) / 256, 256, 0, stream>>>(srcs, dinv, esrc, E);

  // ---- layer 1 ----
  k_gemm1m<<<512, 256, 0, stream>>>(x, W1, h1, n, (n + 15) / 16);
  k_gather64<<<(n + 3) / 4, 256, 0, stream>>>(h1, esrc, rowptr, degi, dinv, b1,
                                              agg1, n);

  // ---- layer 2 ----
  k_gemm2<<<(n + 255) / 256, 256, 0, stream>>>(agg1, W2, h2, n);
  k_gather16<<<(n + 15) / 16, 256, 0, stream>>>(h2, esrc, rowptr, degi, dinv, b2,
                                                out, n);
}

// Round 14
// 130.834 us; speedup vs baseline: 2.7878x; 1.0780x over previous
//
#include <hip/hip_runtime.h>
#include <math.h>

#define DIM_IN 128
#define DIM_H 64
#define DIM_OUT 16
#define NBSHIFT 8  // 256 nodes per bucket
#define CHUNK 4096
#define PACKBLKS 256

typedef __attribute__((ext_vector_type(8))) short bf16x8;
typedef __attribute__((ext_vector_type(4))) float f32x4;
typedef __attribute__((ext_vector_type(2))) float f32x2;

__device__ __forceinline__ ushort f2bf(float f) {
  uint u = __float_as_uint(f);
  return (ushort)((u + 0x7FFF + ((u >> 16) & 1)) >> 16);
}
__device__ __forceinline__ float bf2f(ushort s) {
  return __uint_as_float(((uint)s) << 16);
}
__device__ __forceinline__ uint cvtpk(float lo, float hi) {
  uint r;
  asm("v_cvt_pk_bf16_f32 %0, %1, %2" : "=v"(r) : "v"(lo), "v"(hi));
  return r;
}
// 2x f32 -> 2x fp8(e4m3 on gfx950) in [15:0]
__device__ __forceinline__ uint f2fp8pk(float a, float b) {
  uint r = 0;
  asm("v_cvt_pk_fp8_f32 %0, %1, %2" : "+v"(r) : "v"(a), "v"(b));
  return r & 0xffffu;
}
// decode 2x fp8 from u[15:0]
__device__ __forceinline__ f32x2 fp8pk2f(uint u) {
  f32x2 r;
  asm("v_cvt_pk_f32_fp8 %0, %1" : "=v"(r) : "v"(u));
  return r;
}

// ============ CSR build: per-chunk hist -> scans -> partition (atomic-free) ====

__global__ __launch_bounds__(256) void k_hist1(const int* __restrict__ dst, int E,
                                               int* __restrict__ chunkhist) {
  __shared__ int lh[512];
  int t = threadIdx.x;
  int c = blockIdx.x;
  lh[t] = 0;
  lh[t + 256] = 0;
  __syncthreads();
  int e0 = c * CHUNK;
  int e1 = min(E, e0 + CHUNK);
  for (int i = e0 + t; i < e1; i += 256) atomicAdd(&lh[dst[i] >> NBSHIFT], 1);
  __syncthreads();
  chunkhist[c * 512 + t] = lh[t];
  chunkhist[c * 512 + t + 256] = lh[t + 256];
}

// per-bucket exclusive scan across chunks (block b = bucket b; NC <= 512)
__global__ __launch_bounds__(512) void k_scanc(const int* __restrict__ chunkhist,
                                               int NC, int* __restrict__ cstart,
                                               int* __restrict__ gbhist) {
  __shared__ int sc[512];
  int t = threadIdx.x;
  int b = blockIdx.x;
  int v = (t < NC) ? chunkhist[t * 512 + b] : 0;
  sc[t] = v;
  __syncthreads();
  for (int off = 1; off < 512; off <<= 1) {
    int add = (t >= off) ? sc[t - off] : 0;
    __syncthreads();
    sc[t] += add;
    __syncthreads();
  }
  if (t < NC) cstart[t * 512 + b] = sc[t] - v;
  if (t == 511) gbhist[b] = sc[511];
}

__global__ __launch_bounds__(512) void k_bscan(const int* __restrict__ gbhist,
                                               int* __restrict__ bbase) {
  __shared__ int sb[512];
  int t = threadIdx.x;
  int v = gbhist[t];
  sb[t] = v;
  __syncthreads();
  for (int off = 1; off < 512; off <<= 1) {
    int add = (t >= off) ? sb[t - off] : 0;
    __syncthreads();
    sb[t] += add;
    __syncthreads();
  }
  bbase[t] = sb[t] - v;
}

// pairs packed: (src << 8) | (dst & 255)
__global__ __launch_bounds__(256) void k_part2(const int* __restrict__ src,
                                               const int* __restrict__ dst, int E,
                                               const int* __restrict__ cstart,
                                               const int* __restrict__ bbase,
                                               uint* __restrict__ pairs) {
  __shared__ int lcur[512];
  int t = threadIdx.x;
  int c = blockIdx.x;
  lcur[t] = cstart[c * 512 + t] + bbase[t];
  lcur[t + 256] = cstart[c * 512 + t + 256] + bbase[t + 256];
  __syncthreads();
  int e0 = c * CHUNK;
  int e1 = min(E, e0 + CHUNK);
  for (int i = e0 + t; i < e1; i += 256) {
    int d = dst[i];
    int pos = atomicAdd(&lcur[d >> NBSHIFT], 1);
    pairs[pos] = ((uint)src[i] << 8) | ((uint)d & 255u);
  }
}

__global__ __launch_bounds__(256) void k_csr(const uint* __restrict__ pairs,
                                             const int* __restrict__ gbhist,
                                             const int* __restrict__ bbase, int n,
                                             int* __restrict__ degi,
                                             float* __restrict__ dinv,
                                             int* __restrict__ rowptr,
                                             int* __restrict__ srcs) {
  __shared__ int nh[256];
  __shared__ int ncur[256];
  int t = threadIdx.x;
  int b = blockIdx.x;
  int base = bbase[b];
  int cnt = gbhist[b];
  nh[t] = 0;
  __syncthreads();
  for (int i = t; i < cnt; i += 256) atomicAdd(&nh[pairs[base + i] & 255u], 1);
  __syncthreads();
  int node = (b << NBSHIFT) + t;
  int v = nh[t];
  if (node < n) {
    degi[node] = v;
    dinv[node] = rsqrtf((float)v + 1.0f);
  }
  __syncthreads();
  for (int off = 1; off < 256; off <<= 1) {
    int add = (t >= off) ? nh[t - off] : 0;
    __syncthreads();
    nh[t] += add;
    __syncthreads();
  }
  int excl = nh[t] - v;
  if (node < n) rowptr[node] = base + excl;
  ncur[t] = base + excl;
  __syncthreads();
  for (int i = t; i < cnt; i += 256) {
    uint p = pairs[base + i];
    int pos = atomicAdd(&ncur[p & 255u], 1);
    srcs[pos] = (int)(p >> 8);
  }
}

// ===== merged: esrc pack (blocks 0..PACKBLKS-1) + GEMM1 MFMA (rest) =====
// esrc[i] = (bf16(dinv[srcs[i]]) << 17) | srcs[i]
// h1 = x @ W1 in fp8 e4m3.
__global__ __launch_bounds__(256, 4) void k_pack_gemm1(
    const int* __restrict__ srcs, const float* __restrict__ dinv,
    uint* __restrict__ esrc, int E, const float* __restrict__ x,
    const float* __restrict__ W, uchar* __restrict__ h, int n, int nTiles) {
  const int t = threadIdx.x;
  if (blockIdx.x < PACKBLKS) {
    const int stride = PACKBLKS * 256;
    for (int i = blockIdx.x * 256 + t; i < E; i += stride) {
      uint s = (uint)srcs[i];
      esrc[i] = ((uint)f2bf(dinv[s]) << 17) | s;
    }
    return;
  }
  const int lane = t & 63;
  const int wid = (blockIdx.x - PACKBLKS) * 4 + (t >> 6);
  const int nW = (gridDim.x - PACKBLKS) * 4;
  const int cc = lane & 15;
  const int kb = (lane >> 4) * 8;

  bf16x8 bfrag[4][4];
#pragma unroll
  for (int kc = 0; kc < 4; ++kc)
#pragma unroll
    for (int nt = 0; nt < 4; ++nt) {
      union { bf16x8 v; uint u[4]; } fb;
#pragma unroll
      for (int j = 0; j < 4; ++j) {
        float lo = W[(size_t)(kc * 32 + kb + 2 * j) * DIM_H + nt * 16 + cc];
        float hi = W[(size_t)(kc * 32 + kb + 2 * j + 1) * DIM_H + nt * 16 + cc];
        fb.u[j] = cvtpk(lo, hi);
      }
      bfrag[kc][nt] = fb.v;
    }

  for (int tile = wid; tile < nTiles; tile += nW) {
    int row0 = tile * 16;
    int ra = row0 + cc;
    if (ra > n - 1) ra = n - 1;
    const float* xp = x + (size_t)ra * DIM_IN;
    f32x4 acc[4] = {{0.f, 0.f, 0.f, 0.f},
                    {0.f, 0.f, 0.f, 0.f},
                    {0.f, 0.f, 0.f, 0.f},
                    {0.f, 0.f, 0.f, 0.f}};
#pragma unroll
    for (int kc = 0; kc < 4; ++kc) {
      float4 a0 = *(const float4*)(xp + kc * 32 + kb);
      float4 a1 = *(const float4*)(xp + kc * 32 + kb + 4);
      union { bf16x8 v; uint u[4]; } fa;
      fa.u[0] = cvtpk(a0.x, a0.y);
      fa.u[1] = cvtpk(a0.z, a0.w);
      fa.u[2] = cvtpk(a1.x, a1.y);
      fa.u[3] = cvtpk(a1.z, a1.w);
#pragma unroll
      for (int nt = 0; nt < 4; ++nt)
        acc[nt] = __builtin_amdgcn_mfma_f32_16x16x32_bf16(fa.v, bfrag[kc][nt],
                                                          acc[nt], 0, 0, 0);
    }
    int rbase = row0 + (lane >> 4) * 4;
#pragma unroll
    for (int nt = 0; nt < 4; ++nt) {
      int col = nt * 16 + cc;
      uint w01 = f2fp8pk(acc[nt][0], acc[nt][1]);
      uint w23 = f2fp8pk(acc[nt][2], acc[nt][3]);
      uchar bytes[4] = {(uchar)(w01 & 0xff), (uchar)(w01 >> 8),
                        (uchar)(w23 & 0xff), (uchar)(w23 >> 8)};
#pragma unroll
      for (int j = 0; j < 4; ++j) {
        int r = rbase + j;
        if (r < n) h[(size_t)r * DIM_H + col] = bytes[j];
      }
    }
  }
}

// ============ GEMM2: h2(bf16) = agg1r(bf16, already relu'd) @ W2 ============
__global__ __launch_bounds__(256) void k_gemm2(const ushort* __restrict__ a,
                                               const float* __restrict__ W,
                                               ushort* __restrict__ h2, int n) {
  __shared__ float Ws[64][16];
  const int t = threadIdx.x;
  for (int i = t; i < 64 * 16; i += 256) Ws[i >> 4][i & 15] = W[i];
  __syncthreads();
  int r = blockIdx.x * 256 + t;
  if (r >= n) return;
  const uint4* ap = (const uint4*)(a + (size_t)r * DIM_H);
  float acc[16] = {};
#pragma unroll
  for (int k8 = 0; k8 < 8; ++k8) {
    uint4 v = ap[k8];
    uint w[4] = {v.x, v.y, v.z, v.w};
#pragma unroll
    for (int p = 0; p < 4; ++p) {
      float v0 = bf2f((ushort)(w[p] & 0xffff));
      float v1 = bf2f((ushort)(w[p] >> 16));
      int k = k8 * 8 + p * 2;
#pragma unroll
      for (int j = 0; j < 16; ++j) acc[j] = fmaf(v0, Ws[k][j], acc[j]);
#pragma unroll
      for (int j = 0; j < 16; ++j) acc[j] = fmaf(v1, Ws[k + 1][j], acc[j]);
    }
  }
  ushort4* hp = (ushort4*)(h2 + (size_t)r * DIM_OUT);
#pragma unroll
  for (int q = 0; q < 4; ++q) {
    ushort4 o;
    o.x = f2bf(acc[q * 4 + 0]);
    o.y = f2bf(acc[q * 4 + 1]);
    o.z = f2bf(acc[q * 4 + 2]);
    o.w = f2bf(acc[q * 4 + 3]);
    hp[q] = o;
  }
}

// ======================= gather aggregation =======================

// layer 1: one wave per node; q=lane&15 owns cols 4q..4q+3 (uint = 4 fp8),
// g=lane>>4 walks edges j+g, j+4+g, j+8+g, j+12+g. esrc packed. Output is
// relu(agg + self + bias) in bf16.
__global__ __launch_bounds__(256) void k_gather64(const uchar* __restrict__ h,
                                                  const uint* __restrict__ esrc,
                                                  const int* __restrict__ rowptr,
                                                  const int* __restrict__ deg,
                                                  const float* __restrict__ dinv,
                                                  const float* __restrict__ b,
                                                  ushort* __restrict__ out, int n) {
  int node = blockIdx.x * 4 + (threadIdx.x >> 6);
  int lane = threadIdx.x & 63;
  int g = lane >> 4;
  int q = lane & 15;
  if (node >= n) return;
  int start = rowptr[node];
  int cnt = deg[node];
  float dd = dinv[node];
  float a0 = 0.f, a1 = 0.f, a2 = 0.f, a3 = 0.f;
  for (int j0 = 0; j0 < cnt; j0 += 64) {
    int rem = cnt - j0;
    if (rem > 64) rem = 64;
    uint p_l = (lane < rem) ? esrc[start + j0 + lane] : 0u;
    int s_l = (int)(p_l & 0x1FFFFu);
    float w_l = bf2f((ushort)(p_l >> 17)) * dd;  // 0 for padded lanes
    for (int j = 0; j < rem; j += 16) {
      int i0 = j + g, i1 = j + 4 + g, i2 = j + 8 + g, i3 = j + 12 + g;
      int s0 = __shfl(s_l, i0);
      float w0 = __shfl(w_l, i0);
      int s1 = __shfl(s_l, i1);
      float w1 = __shfl(w_l, i1);
      int s2 = __shfl(s_l, i2);
      float w2 = __shfl(w_l, i2);
      int s3 = __shfl(s_l, i3);
      float w3 = __shfl(w_l, i3);
      uint v0 = *(const uint*)(h + (size_t)s0 * DIM_H + q * 4);
      uint v1 = *(const uint*)(h + (size_t)s1 * DIM_H + q * 4);
      uint v2 = *(const uint*)(h + (size_t)s2 * DIM_H + q * 4);
      uint v3 = *(const uint*)(h + (size_t)s3 * DIM_H + q * 4);
      f32x2 l0 = fp8pk2f(v0), h0 = fp8pk2f(v0 >> 16);
      f32x2 l1 = fp8pk2f(v1), h1v = fp8pk2f(v1 >> 16);
      f32x2 l2 = fp8pk2f(v2), h2v = fp8pk2f(v2 >> 16);
      f32x2 l3 = fp8pk2f(v3), h3v = fp8pk2f(v3 >> 16);
      a0 = fmaf(l0.x, w0, a0);
      a1 = fmaf(l0.y, w0, a1);
      a2 = fmaf(h0.x, w0, a2);
      a3 = fmaf(h0.y, w0, a3);
      a0 = fmaf(l1.x, w1, a0);
      a1 = fmaf(l1.y, w1, a1);
      a2 = fmaf(h1v.x, w1, a2);
      a3 = fmaf(h1v.y, w1, a3);
      a0 = fmaf(l2.x, w2, a0);
      a1 = fmaf(l2.y, w2, a1);
      a2 = fmaf(h2v.x, w2, a2);
      a3 = fmaf(h2v.y, w2, a3);
      a0 = fmaf(l3.x, w3, a0);
      a1 = fmaf(l3.y, w3, a1);
      a2 = fmaf(h3v.x, w3, a2);
      a3 = fmaf(h3v.y, w3, a3);
    }
  }
  a0 += __shfl_xor(a0, 16); a0 += __shfl_xor(a0, 32);
  a1 += __shfl_xor(a1, 16); a1 += __shfl_xor(a1, 32);
  a2 += __shfl_xor(a2, 16); a2 += __shfl_xor(a2, 32);
  a3 += __shfl_xor(a3, 16); a3 += __shfl_xor(a3, 32);
  if (g == 0) {
    uint sv = *(const uint*)(h + (size_t)node * DIM_H + q * 4);
    f32x2 slo = fp8pk2f(sv), shi = fp8pk2f(sv >> 16);
    float s2 = dd * dd;
    a0 = fmaxf(fmaf(slo.x, s2, a0) + b[4 * q + 0], 0.f);
    a1 = fmaxf(fmaf(slo.y, s2, a1) + b[4 * q + 1], 0.f);
    a2 = fmaxf(fmaf(shi.x, s2, a2) + b[4 * q + 2], 0.f);
    a3 = fmaxf(fmaf(shi.y, s2, a3) + b[4 * q + 3], 0.f);
    uint lo = cvtpk(a0, a1);
    uint hi = cvtpk(a2, a3);
    *(uint2*)(out + (size_t)node * DIM_H + q * 4) = make_uint2(lo, hi);
  }
}

// layer 2: 16 lanes per node; c=lane&3 owns cols 4c..4c+3, e=(lane>>2)&3 picks
// edges e,4+e,8+e,12+e. esrc packed. Fused self+bias+log_softmax. out f32.
__global__ __launch_bounds__(256) void k_gather16(const ushort* __restrict__ h,
                                                  const uint* __restrict__ esrc,
                                                  const int* __restrict__ rowptr,
                                                  const int* __restrict__ deg,
                                                  const float* __restrict__ dinv,
                                                  const float* __restrict__ b,
                                                  float* __restrict__ out, int n) {
  int node = blockIdx.x * 16 + (threadIdx.x >> 4);
  int lane = threadIdx.x & 63;
  int lane16 = lane & 15;
  int gbase = lane & 48;
  int e = (lane >> 2) & 3;
  int c = lane & 3;
  if (node >= n) return;
  int start = rowptr[node];
  int cnt = deg[node];
  float dd = dinv[node];
  const int iA = gbase + e, iB = gbase + 4 + e, iC = gbase + 8 + e,
            iD = gbase + 12 + e;
  float a0 = 0.f, a1 = 0.f, a2 = 0.f, a3 = 0.f;
  for (int j0 = 0; j0 < cnt; j0 += 16) {
    int rem = cnt - j0;
    if (rem > 16) rem = 16;
    uint p_l = (lane16 < rem) ? esrc[start + j0 + lane16] : 0u;
    int s_l = (int)(p_l & 0x1FFFFu);
    float w_l = bf2f((ushort)(p_l >> 17)) * dd;
    int sA = __shfl(s_l, iA);
    float wA = __shfl(w_l, iA);
    int sB = __shfl(s_l, iB);
    float wB = __shfl(w_l, iB);
    int sC = __shfl(s_l, iC);
    float wC = __shfl(w_l, iC);
    int sD = __shfl(s_l, iD);
    float wD = __shfl(w_l, iD);
    uint2 vA = *(const uint2*)(h + (size_t)sA * DIM_OUT + c * 4);
    uint2 vB = *(const uint2*)(h + (size_t)sB * DIM_OUT + c * 4);
    uint2 vC = *(const uint2*)(h + (size_t)sC * DIM_OUT + c * 4);
    uint2 vD = *(const uint2*)(h + (size_t)sD * DIM_OUT + c * 4);
    a0 = fmaf(bf2f((ushort)(vA.x & 0xffff)), wA, a0);
    a1 = fmaf(bf2f((ushort)(vA.x >> 16)), wA, a1);
    a2 = fmaf(bf2f((ushort)(vA.y & 0xffff)), wA, a2);
    a3 = fmaf(bf2f((ushort)(vA.y >> 16)), wA, a3);
    a0 = fmaf(bf2f((ushort)(vB.x & 0xffff)), wB, a0);
    a1 = fmaf(bf2f((ushort)(vB.x >> 16)), wB, a1);
    a2 = fmaf(bf2f((ushort)(vB.y & 0xffff)), wB, a2);
    a3 = fmaf(bf2f((ushort)(vB.y >> 16)), wB, a3);
    a0 = fmaf(bf2f((ushort)(vC.x & 0xffff)), wC, a0);
    a1 = fmaf(bf2f((ushort)(vC.x >> 16)), wC, a1);
    a2 = fmaf(bf2f((ushort)(vC.y & 0xffff)), wC, a2);
    a3 = fmaf(bf2f((ushort)(vC.y >> 16)), wC, a3);
    a0 = fmaf(bf2f((ushort)(vD.x & 0xffff)), wD, a0);
    a1 = fmaf(bf2f((ushort)(vD.x >> 16)), wD, a1);
    a2 = fmaf(bf2f((ushort)(vD.y & 0xffff)), wD, a2);
    a3 = fmaf(bf2f((ushort)(vD.y >> 16)), wD, a3);
  }
  a0 += __shfl_xor(a0, 4); a0 += __shfl_xor(a0, 8);
  a1 += __shfl_xor(a1, 4); a1 += __shfl_xor(a1, 8);
  a2 += __shfl_xor(a2, 4); a2 += __shfl_xor(a2, 8);
  a3 += __shfl_xor(a3, 4); a3 += __shfl_xor(a3, 8);
  uint2 sv = *(const uint2*)(h + (size_t)node * DIM_OUT + c * 4);
  float s2 = dd * dd;
  a0 = fmaf(bf2f((ushort)(sv.x & 0xffff)), s2, a0) + b[4 * c + 0];
  a1 = fmaf(bf2f((ushort)(sv.x >> 16)), s2, a1) + b[4 * c + 1];
  a2 = fmaf(bf2f((ushort)(sv.y & 0xffff)), s2, a2) + b[4 * c + 2];
  a3 = fmaf(bf2f((ushort)(sv.y >> 16)), s2, a3) + b[4 * c + 3];
  float m = fmaxf(fmaxf(a0, a1), fmaxf(a2, a3));
  m = fmaxf(m, __shfl_xor(m, 1));
  m = fmaxf(m, __shfl_xor(m, 2));
  float ssum = expf(a0 - m) + expf(a1 - m) + expf(a2 - m) + expf(a3 - m);
  ssum += __shfl_xor(ssum, 1);
  ssum += __shfl_xor(ssum, 2);
  float l = m + logf(ssum);
  if (e == 0)
    *(float4*)(out + (size_t)node * DIM_OUT + c * 4) =
        make_float4(a0 - l, a1 - l, a2 - l, a3 - l);
}

// ======================= launch =======================

extern "C" void kernel_launch(void* const* d_in, const int* in_sizes, int n_in,
                              void* d_out, int out_size, void* d_ws, size_t ws_size,
                              hipStream_t stream) {
  const float* x  = (const float*)d_in[0];
  const int*   ei = (const int*)d_in[1];
  const float* W1 = (const float*)d_in[2];
  const float* b1 = (const float*)d_in[3];
  const float* W2 = (const float*)d_in[4];
  const float* b2 = (const float*)d_in[5];
  float* out = (float*)d_out;

  const int n = in_sizes[0] / DIM_IN;  // 100000
  const int E = in_sizes[1] / 2;       // 1600000
  const int* srcv = ei;
  const int* dstv = ei + E;
  const int NB = (n + 255) >> NBSHIFT;     // 391
  const int NC = (E + CHUNK - 1) / CHUNK;  // 391 (<=512)

  char* wsb = (char*)d_ws;
  int* degi      = (int*)wsb;   wsb += (size_t)n * 4;
  int* rowptr    = (int*)wsb;   wsb += (size_t)n * 4;
  float* dinv    = (float*)wsb; wsb += (size_t)n * 4;
  int* gbhist    = (int*)wsb;   wsb += 512 * 4;
  int* bbase     = (int*)wsb;   wsb += 512 * 4;
  int* chunkhist = (int*)wsb;   wsb += (size_t)512 * 512 * 4;
  int* cstart    = (int*)wsb;   wsb += (size_t)512 * 512 * 4;
  int* srcs      = (int*)wsb;   wsb += (size_t)E * 4;
  uint* esrc     = (uint*)wsb;  wsb += (size_t)E * 4;
  uchar* h1      = (uchar*)wsb; wsb += (size_t)n * DIM_H;       // fp8
  ushort* agg1   = (ushort*)wsb; wsb += (size_t)n * DIM_H * 2;  // bf16
  ushort* h2     = (ushort*)wsb; wsb += (size_t)n * DIM_OUT * 2;
  // pairs (E uint = 6.4 MB) aliases agg1 (12.8 MB): dead before k_gather64 writes
  uint* pairs = (uint*)agg1;

  // ---- CSR build (deterministic, separate kernels) ----
  k_hist1<<<NC, 256, 0, stream>>>(dstv, E, chunkhist);
  k_scanc<<<512, 512, 0, stream>>>(chunkhist, NC, cstart, gbhist);
  k_bscan<<<1, 512, 0, stream>>>(gbhist, bbase);
  k_part2<<<NC, 256, 0, stream>>>(srcv, dstv, E, cstart, bbase, pairs);
  k_csr<<<NB, 256, 0, stream>>>(pairs, gbhist, bbase, n, degi, dinv, rowptr, srcs);

  // ---- esrc pack + layer-1 GEMM (merged, independent halves) ----
  k_pack_gemm1<<<PACKBLKS + 512, 256, 0, stream>>>(srcs, dinv, esrc, E, x, W1, h1,
                                                   n, (n + 15) / 16);

  // ---- layer 1 aggregation (+relu, bf16 out) ----
  k_gather64<<<(n + 3) / 4, 256, 0, stream>>>(h1, esrc, rowptr, degi, dinv, b1,
                                              agg1, n);

  // ---- layer 2 ----
  k_gemm2<<<(n + 255) / 256, 256, 0, stream>>>(agg1, W2, h2, n);
  k_gather16<<<(n + 15) / 16, 256, 0, stream>>>(h2, esrc, rowptr, degi, dinv, b2,
                                                out, n);
}

// Round 15
// 128.433 us; speedup vs baseline: 2.8400x; 1.0187x over previous
//
#include <hip/hip_runtime.h>
#include <math.h>

#define DIM_IN 128
#define DIM_H 64
#define DIM_OUT 16
#define NBSHIFT 8  // 256 nodes per bucket
#define CHUNK 4096
#define PACKBLKS 256

typedef __attribute__((ext_vector_type(8))) short bf16x8;
typedef __attribute__((ext_vector_type(4))) float f32x4;
typedef __attribute__((ext_vector_type(2))) float f32x2;

__device__ __forceinline__ ushort f2bf(float f) {
  uint u = __float_as_uint(f);
  return (ushort)((u + 0x7FFF + ((u >> 16) & 1)) >> 16);
}
__device__ __forceinline__ float bf2f(ushort s) {
  return __uint_as_float(((uint)s) << 16);
}
__device__ __forceinline__ uint cvtpk(float lo, float hi) {
  uint r;
  asm("v_cvt_pk_bf16_f32 %0, %1, %2" : "=v"(r) : "v"(lo), "v"(hi));
  return r;
}
// 2x f32 -> 2x fp8(e4m3 on gfx950) in [15:0]
__device__ __forceinline__ uint f2fp8pk(float a, float b) {
  uint r = 0;
  asm("v_cvt_pk_fp8_f32 %0, %1, %2" : "+v"(r) : "v"(a), "v"(b));
  return r & 0xffffu;
}
// decode 2x fp8 from u[15:0]
__device__ __forceinline__ f32x2 fp8pk2f(uint u) {
  f32x2 r;
  asm("v_cvt_pk_f32_fp8 %0, %1" : "=v"(r) : "v"(u));
  return r;
}

// ============ CSR build: per-chunk hist -> scans -> partition (atomic-free) ====

__global__ __launch_bounds__(256) void k_hist1(const int* __restrict__ dst, int E,
                                               int* __restrict__ chunkhist) {
  __shared__ int lh[512];
  int t = threadIdx.x;
  int c = blockIdx.x;
  lh[t] = 0;
  lh[t + 256] = 0;
  __syncthreads();
  int e0 = c * CHUNK;
  int e1 = min(E, e0 + CHUNK);
  for (int i = e0 + t; i < e1; i += 256) atomicAdd(&lh[dst[i] >> NBSHIFT], 1);
  __syncthreads();
  chunkhist[c * 512 + t] = lh[t];
  chunkhist[c * 512 + t + 256] = lh[t + 256];
}

// per-bucket exclusive scan across chunks (block b = bucket b; NC <= 512)
__global__ __launch_bounds__(512) void k_scanc(const int* __restrict__ chunkhist,
                                               int NC, int* __restrict__ cstart,
                                               int* __restrict__ gbhist) {
  __shared__ int sc[512];
  int t = threadIdx.x;
  int b = blockIdx.x;
  int v = (t < NC) ? chunkhist[t * 512 + b] : 0;
  sc[t] = v;
  __syncthreads();
  for (int off = 1; off < 512; off <<= 1) {
    int add = (t >= off) ? sc[t - off] : 0;
    __syncthreads();
    sc[t] += add;
    __syncthreads();
  }
  if (t < NC) cstart[t * 512 + b] = sc[t] - v;
  if (t == 511) gbhist[b] = sc[511];
}

// partition into bucket regions; bbase self-computed from gbhist (LDS scan).
// pairs packed: (src << 8) | (dst & 255)
__global__ __launch_bounds__(256) void k_part2(const int* __restrict__ src,
                                               const int* __restrict__ dst, int E,
                                               const int* __restrict__ cstart,
                                               const int* __restrict__ gbhist,
                                               uint* __restrict__ pairs) {
  __shared__ int sb[512];
  __shared__ int lcur[512];
  int t = threadIdx.x;
  int c = blockIdx.x;
  // 512-wide exclusive scan of gbhist with 256 threads (two halves + carry)
  int v0 = gbhist[t], v1 = gbhist[t + 256];
  sb[t] = v0;
  sb[t + 256] = v1;
  __syncthreads();
  for (int off = 1; off < 256; off <<= 1) {
    int a0 = (t >= off) ? sb[t - off] : 0;
    int a1 = (t >= off) ? sb[256 + t - off] : 0;
    __syncthreads();
    sb[t] += a0;
    sb[256 + t] += a1;
    __syncthreads();
  }
  int tot0 = sb[255];
  lcur[t] = cstart[c * 512 + t] + sb[t] - v0;
  lcur[t + 256] = cstart[c * 512 + t + 256] + sb[256 + t] - v1 + tot0;
  __syncthreads();
  int e0 = c * CHUNK;
  int e1 = min(E, e0 + CHUNK);
  for (int i = e0 + t; i < e1; i += 256) {
    int d = dst[i];
    int pos = atomicAdd(&lcur[d >> NBSHIFT], 1);
    pairs[pos] = ((uint)src[i] << 8) | ((uint)d & 255u);
  }
}

// per-bucket CSR + deg + dinv; base self-computed (masked reduce of gbhist).
__global__ __launch_bounds__(256) void k_csr(const uint* __restrict__ pairs,
                                             const int* __restrict__ gbhist, int n,
                                             int* __restrict__ degi,
                                             float* __restrict__ dinv,
                                             int* __restrict__ rowptr,
                                             int* __restrict__ srcs) {
  __shared__ int nh[256];
  __shared__ int ncur[256];
  __shared__ int red[256];
  int t = threadIdx.x;
  int b = blockIdx.x;
  // base = sum(gbhist[0..b-1])
  int p = 0;
  if (t < b) p += gbhist[t];
  if (t + 256 < b) p += gbhist[t + 256];
  red[t] = p;
  __syncthreads();
  for (int s = 128; s > 0; s >>= 1) {
    if (t < s) red[t] += red[t + s];
    __syncthreads();
  }
  int base = red[0];
  int cnt = gbhist[b];
  nh[t] = 0;
  __syncthreads();
  for (int i = t; i < cnt; i += 256) atomicAdd(&nh[pairs[base + i] & 255u], 1);
  __syncthreads();
  int node = (b << NBSHIFT) + t;
  int v = nh[t];
  if (node < n) {
    degi[node] = v;
    dinv[node] = rsqrtf((float)v + 1.0f);
  }
  __syncthreads();
  for (int off = 1; off < 256; off <<= 1) {
    int add = (t >= off) ? nh[t - off] : 0;
    __syncthreads();
    nh[t] += add;
    __syncthreads();
  }
  int excl = nh[t] - v;
  if (node < n) rowptr[node] = base + excl;
  ncur[t] = base + excl;
  __syncthreads();
  for (int i = t; i < cnt; i += 256) {
    uint pr = pairs[base + i];
    int pos = atomicAdd(&ncur[pr & 255u], 1);
    srcs[pos] = (int)(pr >> 8);
  }
}

// ===== merged: esrc pack (blocks 0..PACKBLKS-1) + GEMM1 MFMA (rest) =====
// esrc[i] = (bf16(dinv[srcs[i]]) << 17) | srcs[i]
// h1 = x @ W1 in fp8 e4m3.
__global__ __launch_bounds__(256, 4) void k_pack_gemm1(
    const int* __restrict__ srcs, const float* __restrict__ dinv,
    uint* __restrict__ esrc, int E, const float* __restrict__ x,
    const float* __restrict__ W, uchar* __restrict__ h, int n, int nTiles) {
  const int t = threadIdx.x;
  if (blockIdx.x < PACKBLKS) {
    const int stride = PACKBLKS * 256;
    for (int i = blockIdx.x * 256 + t; i < E; i += stride) {
      uint s = (uint)srcs[i];
      esrc[i] = ((uint)f2bf(dinv[s]) << 17) | s;
    }
    return;
  }
  const int lane = t & 63;
  const int wid = (blockIdx.x - PACKBLKS) * 4 + (t >> 6);
  const int nW = (gridDim.x - PACKBLKS) * 4;
  const int cc = lane & 15;
  const int kb = (lane >> 4) * 8;

  bf16x8 bfrag[4][4];
#pragma unroll
  for (int kc = 0; kc < 4; ++kc)
#pragma unroll
    for (int nt = 0; nt < 4; ++nt) {
      union { bf16x8 v; uint u[4]; } fb;
#pragma unroll
      for (int j = 0; j < 4; ++j) {
        float lo = W[(size_t)(kc * 32 + kb + 2 * j) * DIM_H + nt * 16 + cc];
        float hi = W[(size_t)(kc * 32 + kb + 2 * j + 1) * DIM_H + nt * 16 + cc];
        fb.u[j] = cvtpk(lo, hi);
      }
      bfrag[kc][nt] = fb.v;
    }

  for (int tile = wid; tile < nTiles; tile += nW) {
    int row0 = tile * 16;
    int ra = row0 + cc;
    if (ra > n - 1) ra = n - 1;
    const float* xp = x + (size_t)ra * DIM_IN;
    f32x4 acc[4] = {{0.f, 0.f, 0.f, 0.f},
                    {0.f, 0.f, 0.f, 0.f},
                    {0.f, 0.f, 0.f, 0.f},
                    {0.f, 0.f, 0.f, 0.f}};
#pragma unroll
    for (int kc = 0; kc < 4; ++kc) {
      float4 a0 = *(const float4*)(xp + kc * 32 + kb);
      float4 a1 = *(const float4*)(xp + kc * 32 + kb + 4);
      union { bf16x8 v; uint u[4]; } fa;
      fa.u[0] = cvtpk(a0.x, a0.y);
      fa.u[1] = cvtpk(a0.z, a0.w);
      fa.u[2] = cvtpk(a1.x, a1.y);
      fa.u[3] = cvtpk(a1.z, a1.w);
#pragma unroll
      for (int nt = 0; nt < 4; ++nt)
        acc[nt] = __builtin_amdgcn_mfma_f32_16x16x32_bf16(fa.v, bfrag[kc][nt],
                                                          acc[nt], 0, 0, 0);
    }
    int rbase = row0 + (lane >> 4) * 4;
#pragma unroll
    for (int nt = 0; nt < 4; ++nt) {
      int col = nt * 16 + cc;
      uint w01 = f2fp8pk(acc[nt][0], acc[nt][1]);
      uint w23 = f2fp8pk(acc[nt][2], acc[nt][3]);
      uchar bytes[4] = {(uchar)(w01 & 0xff), (uchar)(w01 >> 8),
                        (uchar)(w23 & 0xff), (uchar)(w23 >> 8)};
#pragma unroll
      for (int j = 0; j < 4; ++j) {
        int r = rbase + j;
        if (r < n) h[(size_t)r * DIM_H + col] = bytes[j];
      }
    }
  }
}

// ====== GEMM2: h2(fp8) = agg1r(bf16, already relu'd) @ W2 ======
__global__ __launch_bounds__(256) void k_gemm2(const ushort* __restrict__ a,
                                               const float* __restrict__ W,
                                               uchar* __restrict__ h2, int n) {
  __shared__ float Ws[64][16];
  const int t = threadIdx.x;
  for (int i = t; i < 64 * 16; i += 256) Ws[i >> 4][i & 15] = W[i];
  __syncthreads();
  int r = blockIdx.x * 256 + t;
  if (r >= n) return;
  const uint4* ap = (const uint4*)(a + (size_t)r * DIM_H);
  float acc[16] = {};
#pragma unroll
  for (int k8 = 0; k8 < 8; ++k8) {
    uint4 v = ap[k8];
    uint w[4] = {v.x, v.y, v.z, v.w};
#pragma unroll
    for (int p = 0; p < 4; ++p) {
      float v0 = bf2f((ushort)(w[p] & 0xffff));
      float v1 = bf2f((ushort)(w[p] >> 16));
      int k = k8 * 8 + p * 2;
#pragma unroll
      for (int j = 0; j < 16; ++j) acc[j] = fmaf(v0, Ws[k][j], acc[j]);
#pragma unroll
      for (int j = 0; j < 16; ++j) acc[j] = fmaf(v1, Ws[k + 1][j], acc[j]);
    }
  }
  uint4 o;
  o.x = f2fp8pk(acc[0], acc[1]) | (f2fp8pk(acc[2], acc[3]) << 16);
  o.y = f2fp8pk(acc[4], acc[5]) | (f2fp8pk(acc[6], acc[7]) << 16);
  o.z = f2fp8pk(acc[8], acc[9]) | (f2fp8pk(acc[10], acc[11]) << 16);
  o.w = f2fp8pk(acc[12], acc[13]) | (f2fp8pk(acc[14], acc[15]) << 16);
  *(uint4*)(h2 + (size_t)r * DIM_OUT) = o;
}

// ======================= gather aggregation =======================

// layer 1: one wave per node; q=lane&15 owns cols 4q..4q+3 (uint = 4 fp8),
// g=lane>>4 walks edges j+g, j+4+g, j+8+g, j+12+g. esrc packed. Output is
// relu(agg + self + bias) in bf16.
__global__ __launch_bounds__(256) void k_gather64(const uchar* __restrict__ h,
                                                  const uint* __restrict__ esrc,
                                                  const int* __restrict__ rowptr,
                                                  const int* __restrict__ deg,
                                                  const float* __restrict__ dinv,
                                                  const float* __restrict__ b,
                                                  ushort* __restrict__ out, int n) {
  int node = blockIdx.x * 4 + (threadIdx.x >> 6);
  int lane = threadIdx.x & 63;
  int g = lane >> 4;
  int q = lane & 15;
  if (node >= n) return;
  int start = rowptr[node];
  int cnt = deg[node];
  float dd = dinv[node];
  float a0 = 0.f, a1 = 0.f, a2 = 0.f, a3 = 0.f;
  for (int j0 = 0; j0 < cnt; j0 += 64) {
    int rem = cnt - j0;
    if (rem > 64) rem = 64;
    uint p_l = (lane < rem) ? esrc[start + j0 + lane] : 0u;
    int s_l = (int)(p_l & 0x1FFFFu);
    float w_l = bf2f((ushort)(p_l >> 17)) * dd;  // 0 for padded lanes
    for (int j = 0; j < rem; j += 16) {
      int i0 = j + g, i1 = j + 4 + g, i2 = j + 8 + g, i3 = j + 12 + g;
      int s0 = __shfl(s_l, i0);
      float w0 = __shfl(w_l, i0);
      int s1 = __shfl(s_l, i1);
      float w1 = __shfl(w_l, i1);
      int s2 = __shfl(s_l, i2);
      float w2 = __shfl(w_l, i2);
      int s3 = __shfl(s_l, i3);
      float w3 = __shfl(w_l, i3);
      uint v0 = *(const uint*)(h + (size_t)s0 * DIM_H + q * 4);
      uint v1 = *(const uint*)(h + (size_t)s1 * DIM_H + q * 4);
      uint v2 = *(const uint*)(h + (size_t)s2 * DIM_H + q * 4);
      uint v3 = *(const uint*)(h + (size_t)s3 * DIM_H + q * 4);
      f32x2 l0 = fp8pk2f(v0), h0 = fp8pk2f(v0 >> 16);
      f32x2 l1 = fp8pk2f(v1), h1v = fp8pk2f(v1 >> 16);
      f32x2 l2 = fp8pk2f(v2), h2v = fp8pk2f(v2 >> 16);
      f32x2 l3 = fp8pk2f(v3), h3v = fp8pk2f(v3 >> 16);
      a0 = fmaf(l0.x, w0, a0);
      a1 = fmaf(l0.y, w0, a1);
      a2 = fmaf(h0.x, w0, a2);
      a3 = fmaf(h0.y, w0, a3);
      a0 = fmaf(l1.x, w1, a0);
      a1 = fmaf(l1.y, w1, a1);
      a2 = fmaf(h1v.x, w1, a2);
      a3 = fmaf(h1v.y, w1, a3);
      a0 = fmaf(l2.x, w2, a0);
      a1 = fmaf(l2.y, w2, a1);
      a2 = fmaf(h2v.x, w2, a2);
      a3 = fmaf(h2v.y, w2, a3);
      a0 = fmaf(l3.x, w3, a0);
      a1 = fmaf(l3.y, w3, a1);
      a2 = fmaf(h3v.x, w3, a2);
      a3 = fmaf(h3v.y, w3, a3);
    }
  }
  a0 += __shfl_xor(a0, 16); a0 += __shfl_xor(a0, 32);
  a1 += __shfl_xor(a1, 16); a1 += __shfl_xor(a1, 32);
  a2 += __shfl_xor(a2, 16); a2 += __shfl_xor(a2, 32);
  a3 += __shfl_xor(a3, 16); a3 += __shfl_xor(a3, 32);
  if (g == 0) {
    uint sv = *(const uint*)(h + (size_t)node * DIM_H + q * 4);
    f32x2 slo = fp8pk2f(sv), shi = fp8pk2f(sv >> 16);
    float s2 = dd * dd;
    a0 = fmaxf(fmaf(slo.x, s2, a0) + b[4 * q + 0], 0.f);
    a1 = fmaxf(fmaf(slo.y, s2, a1) + b[4 * q + 1], 0.f);
    a2 = fmaxf(fmaf(shi.x, s2, a2) + b[4 * q + 2], 0.f);
    a3 = fmaxf(fmaf(shi.y, s2, a3) + b[4 * q + 3], 0.f);
    uint lo = cvtpk(a0, a1);
    uint hi = cvtpk(a2, a3);
    *(uint2*)(out + (size_t)node * DIM_H + q * 4) = make_uint2(lo, hi);
  }
}

// layer 2: 16 lanes per node; c=lane&3 owns cols 4c..4c+3 (uint = 4 fp8),
// e=(lane>>2)&3 picks edges e,4+e,8+e,12+e. Fused self+bias+log_softmax.
__global__ __launch_bounds__(256) void k_gather16(const uchar* __restrict__ h,
                                                  const uint* __restrict__ esrc,
                                                  const int* __restrict__ rowptr,
                                                  const int* __restrict__ deg,
                                                  const float* __restrict__ dinv,
                                                  const float* __restrict__ b,
                                                  float* __restrict__ out, int n) {
  int node = blockIdx.x * 16 + (threadIdx.x >> 4);
  int lane = threadIdx.x & 63;
  int lane16 = lane & 15;
  int gbase = lane & 48;
  int e = (lane >> 2) & 3;
  int c = lane & 3;
  if (node >= n) return;
  int start = rowptr[node];
  int cnt = deg[node];
  float dd = dinv[node];
  const int iA = gbase + e, iB = gbase + 4 + e, iC = gbase + 8 + e,
            iD = gbase + 12 + e;
  float a0 = 0.f, a1 = 0.f, a2 = 0.f, a3 = 0.f;
  for (int j0 = 0; j0 < cnt; j0 += 16) {
    int rem = cnt - j0;
    if (rem > 16) rem = 16;
    uint p_l = (lane16 < rem) ? esrc[start + j0 + lane16] : 0u;
    int s_l = (int)(p_l & 0x1FFFFu);
    float w_l = bf2f((ushort)(p_l >> 17)) * dd;
    int sA = __shfl(s_l, iA);
    float wA = __shfl(w_l, iA);
    int sB = __shfl(s_l, iB);
    float wB = __shfl(w_l, iB);
    int sC = __shfl(s_l, iC);
    float wC = __shfl(w_l, iC);
    int sD = __shfl(s_l, iD);
    float wD = __shfl(w_l, iD);
    uint vA = *(const uint*)(h + (size_t)sA * DIM_OUT + c * 4);
    uint vB = *(const uint*)(h + (size_t)sB * DIM_OUT + c * 4);
    uint vC = *(const uint*)(h + (size_t)sC * DIM_OUT + c * 4);
    uint vD = *(const uint*)(h + (size_t)sD * DIM_OUT + c * 4);
    f32x2 lA = fp8pk2f(vA), hA = fp8pk2f(vA >> 16);
    f32x2 lB = fp8pk2f(vB), hB = fp8pk2f(vB >> 16);
    f32x2 lC = fp8pk2f(vC), hC = fp8pk2f(vC >> 16);
    f32x2 lD = fp8pk2f(vD), hD = fp8pk2f(vD >> 16);
    a0 = fmaf(lA.x, wA, a0);
    a1 = fmaf(lA.y, wA, a1);
    a2 = fmaf(hA.x, wA, a2);
    a3 = fmaf(hA.y, wA, a3);
    a0 = fmaf(lB.x, wB, a0);
    a1 = fmaf(lB.y, wB, a1);
    a2 = fmaf(hB.x, wB, a2);
    a3 = fmaf(hB.y, wB, a3);
    a0 = fmaf(lC.x, wC, a0);
    a1 = fmaf(lC.y, wC, a1);
    a2 = fmaf(hC.x, wC, a2);
    a3 = fmaf(hC.y, wC, a3);
    a0 = fmaf(lD.x, wD, a0);
    a1 = fmaf(lD.y, wD, a1);
    a2 = fmaf(hD.x, wD, a2);
    a3 = fmaf(hD.y, wD, a3);
  }
  a0 += __shfl_xor(a0, 4); a0 += __shfl_xor(a0, 8);
  a1 += __shfl_xor(a1, 4); a1 += __shfl_xor(a1, 8);
  a2 += __shfl_xor(a2, 4); a2 += __shfl_xor(a2, 8);
  a3 += __shfl_xor(a3, 4); a3 += __shfl_xor(a3, 8);
  uint sv = *(const uint*)(h + (size_t)node * DIM_OUT + c * 4);
  f32x2 slo = fp8pk2f(sv), shi = fp8pk2f(sv >> 16);
  float s2 = dd * dd;
  a0 = fmaf(slo.x, s2, a0) + b[4 * c + 0];
  a1 = fmaf(slo.y, s2, a1) + b[4 * c + 1];
  a2 = fmaf(shi.x, s2, a2) + b[4 * c + 2];
  a3 = fmaf(shi.y, s2, a3) + b[4 * c + 3];
  float m = fmaxf(fmaxf(a0, a1), fmaxf(a2, a3));
  m = fmaxf(m, __shfl_xor(m, 1));
  m = fmaxf(m, __shfl_xor(m, 2));
  float ssum = expf(a0 - m) + expf(a1 - m) + expf(a2 - m) + expf(a3 - m);
  ssum += __shfl_xor(ssum, 1);
  ssum += __shfl_xor(ssum, 2);
  float l = m + logf(ssum);
  if (e == 0)
    *(float4*)(out + (size_t)node * DIM_OUT + c * 4) =
        make_float4(a0 - l, a1 - l, a2 - l, a3 - l);
}

// ======================= launch =======================

extern "C" void kernel_launch(void* const* d_in, const int* in_sizes, int n_in,
                              void* d_out, int out_size, void* d_ws, size_t ws_size,
                              hipStream_t stream) {
  const float* x  = (const float*)d_in[0];
  const int*   ei = (const int*)d_in[1];
  const float* W1 = (const float*)d_in[2];
  const float* b1 = (const float*)d_in[3];
  const float* W2 = (const float*)d_in[4];
  const float* b2 = (const float*)d_in[5];
  float* out = (float*)d_out;

  const int n = in_sizes[0] / DIM_IN;  // 100000
  const int E = in_sizes[1] / 2;       // 1600000
  const int* srcv = ei;
  const int* dstv = ei + E;
  const int NB = (n + 255) >> NBSHIFT;     // 391
  const int NC = (E + CHUNK - 1) / CHUNK;  // 391 (<=512)

  char* wsb = (char*)d_ws;
  int* degi      = (int*)wsb;   wsb += (size_t)n * 4;
  int* rowptr    = (int*)wsb;   wsb += (size_t)n * 4;
  float* dinv    = (float*)wsb; wsb += (size_t)n * 4;
  int* gbhist    = (int*)wsb;   wsb += 512 * 4;
  int* chunkhist = (int*)wsb;   wsb += (size_t)512 * 512 * 4;
  int* cstart    = (int*)wsb;   wsb += (size_t)512 * 512 * 4;
  int* srcs      = (int*)wsb;   wsb += (size_t)E * 4;
  uint* esrc     = (uint*)wsb;  wsb += (size_t)E * 4;
  uchar* h1      = (uchar*)wsb; wsb += (size_t)n * DIM_H;       // fp8
  ushort* agg1   = (ushort*)wsb; wsb += (size_t)n * DIM_H * 2;  // bf16
  uchar* h2      = (uchar*)wsb; wsb += (size_t)n * DIM_OUT;     // fp8
  // pairs (E uint = 6.4 MB) aliases agg1 (12.8 MB): dead before k_gather64 writes
  uint* pairs = (uint*)agg1;

  // ---- CSR build (deterministic, separate kernels) ----
  k_hist1<<<NC, 256, 0, stream>>>(dstv, E, chunkhist);
  k_scanc<<<512, 512, 0, stream>>>(chunkhist, NC, cstart, gbhist);
  k_part2<<<NC, 256, 0, stream>>>(srcv, dstv, E, cstart, gbhist, pairs);
  k_csr<<<NB, 256, 0, stream>>>(pairs, gbhist, n, degi, dinv, rowptr, srcs);

  // ---- esrc pack + layer-1 GEMM (merged, independent halves) ----
  k_pack_gemm1<<<PACKBLKS + 512, 256, 0, stream>>>(srcs, dinv, esrc, E, x, W1, h1,
                                                   n, (n + 15) / 16);

  // ---- layer 1 aggregation (+relu, bf16 out) ----
  k_gather64<<<(n + 3) / 4, 256, 0, stream>>>(h1, esrc, rowptr, degi, dinv, b1,
                                              agg1, n);

  // ---- layer 2 ----
  k_gemm2<<<(n + 255) / 256, 256, 0, stream>>>(agg1, W2, h2, n);
  k_gather16<<<(n + 15) / 16, 256, 0, stream>>>(h2, esrc, rowptr, degi, dinv, b2,
                                                out, n);
}